// Round 8
// baseline (839.726 us; speedup 1.0000x reference)
//
#include <hip/hip_runtime.h>
#include <hip/hip_bf16.h>

#define N_NODES 100000
#define N_EDGES 1600000
#define NBUCK   391          // ceil(100000/256) node-buckets of 256

static __device__ __forceinline__ float us2f(unsigned short u) {
    union { unsigned int i; float f; } cv; cv.i = ((unsigned int)u) << 16; return cv.f;
}
static __device__ __forceinline__ unsigned short f2us(float f) {
    __hip_bfloat16 b = __float2bfloat16(f);
    union { __hip_bfloat16 b; unsigned short u; } cv; cv.b = b; return cv.u;
}
static __device__ __forceinline__ float elu_fast(float v) {
    return v > 0.f ? v : (__expf(v) - 1.0f);
}

// ---------------- inv: single-wave Gauss-Jordan; outputs MmT[j*32+c] = (A^T (I-A^T)^{-1})[c][j]
__global__ __launch_bounds__(64) void k_inv(const float* __restrict__ A,
                                            float* __restrict__ MmT) {
    __shared__ float Af[1024];
    __shared__ float aug[32 * 65];
    __shared__ float fac[32];
    __shared__ float pv_s;
    int t = threadIdx.x;
    for (int i = t; i < 1024; i += 64) Af[i] = A[i];
    __syncthreads();
    for (int i = t; i < 2048; i += 64) {
        int r = i >> 6, c = i & 63;
        float v;
        if (c < 32) v = (r == c ? 1.0f : 0.0f) - Af[c * 32 + r];
        else        v = ((c - 32) == r ? 1.0f : 0.0f);
        aug[r * 65 + c] = v;
    }
    __syncthreads();
    for (int k = 0; k < 32; ++k) {
        if (t == 0) pv_s = 1.0f / aug[k * 65 + k];
        __syncthreads();
        aug[k * 65 + t] *= pv_s;
        __syncthreads();
        if (t < 32) fac[t] = aug[t * 65 + k];
        __syncthreads();
        #pragma unroll 4
        for (int i = t; i < 2048; i += 64) {
            int r = i >> 6, c = i & 63;
            if (r != k) aug[r * 65 + c] -= fac[r] * aug[k * 65 + c];
        }
        __syncthreads();
    }
    for (int i = t; i < 1024; i += 64) {
        int j = i >> 5, c = i & 31;
        float s = 0.f;
        #pragma unroll
        for (int k = 0; k < 32; ++k) s += Af[k * 32 + c] * aug[k * 65 + 32 + j];
        MmT[i] = s;
    }
}

// ---------------- fold: Wcomb[h][c*4+d] = sum_j Mm[c][j]*Wm[h*128+j*4+d]  (16 blocks) --------
__global__ __launch_bounds__(256) void k_fold(const float* __restrict__ MmT,
                                              const float* __restrict__ Wm,
                                              float* __restrict__ Wcomb) {
    __shared__ float MmTs[1024];
    int tid = threadIdx.x;
    for (int i = tid; i < 1024; i += 256) MmTs[i] = MmT[i];
    __syncthreads();
    int o = blockIdx.x * 256 + tid;
    int h = o >> 5, c = o & 31;
    float4 s = {0.f, 0.f, 0.f, 0.f};
    #pragma unroll
    for (int j = 0; j < 32; ++j) {
        float m = MmTs[j * 32 + c];
        float4 w = ((const float4*)Wm)[h * 32 + j];
        s.x += m * w.x; s.y += m * w.y; s.z += m * w.z; s.w += m * w.w;
    }
    ((float4*)Wcomb)[o] = s;
}

// ---------------- CSR build: histogram -> multi-block scan ----------------------------------
__global__ __launch_bounds__(256) void k_hist(const int* __restrict__ edst,
                                              unsigned int* __restrict__ deg) {
    int e = blockIdx.x * 256 + threadIdx.x;
    atomicAdd(&deg[edst[e]], 1u);
}

__global__ __launch_bounds__(256) void k_scanA(const unsigned int* __restrict__ deg,
                                               unsigned int* __restrict__ row_start,
                                               unsigned int* __restrict__ blk_sums) {
    __shared__ unsigned int sums[256];
    int tid = threadIdx.x;
    int gid = blockIdx.x * 256 + tid;
    uint4 d = ((const uint4*)deg)[gid];
    unsigned int p1 = d.x, p2 = d.x + d.y, p3 = p2 + d.z;
    unsigned int tsum = p3 + d.w;
    sums[tid] = tsum;
    __syncthreads();
    for (int off = 1; off < 256; off <<= 1) {
        unsigned int v = (tid >= off) ? sums[tid - off] : 0u;
        __syncthreads();
        sums[tid] += v;
        __syncthreads();
    }
    unsigned int excl = sums[tid] - tsum;
    int eb = gid * 4;
    if (eb + 0 < N_NODES) row_start[eb + 0] = excl;
    if (eb + 1 < N_NODES) row_start[eb + 1] = excl + p1;
    if (eb + 2 < N_NODES) row_start[eb + 2] = excl + p2;
    if (eb + 3 < N_NODES) row_start[eb + 3] = excl + p3;
    if (tid == 255) blk_sums[blockIdx.x] = sums[255];
}

__global__ __launch_bounds__(128) void k_scanB(unsigned int* __restrict__ blk_sums) {
    __shared__ unsigned int s[128];
    int tid = threadIdx.x;
    unsigned int v = (tid < 98) ? blk_sums[tid] : 0u;
    s[tid] = v;
    __syncthreads();
    for (int off = 1; off < 128; off <<= 1) {
        unsigned int x = (tid >= off) ? s[tid - off] : 0u;
        __syncthreads();
        s[tid] += x;
        __syncthreads();
    }
    if (tid < 98) blk_sums[tid] = s[tid] - v;
}

__global__ __launch_bounds__(256) void k_scanC(unsigned int* __restrict__ row_start,
                                               unsigned int* __restrict__ cursor,
                                               const unsigned int* __restrict__ blk_sums) {
    int tid = threadIdx.x;
    unsigned int off = blk_sums[blockIdx.x];
    int eb = (blockIdx.x * 256 + tid) * 4;
    #pragma unroll
    for (int k = 0; k < 4; ++k) {
        int idx = eb + k;
        if (idx < N_NODES) {
            unsigned int u = row_start[idx] + off;
            row_start[idx] = u;
            cursor[idx] = u;
        }
    }
    if (blockIdx.x == 0 && tid == 0) row_start[N_NODES] = N_EDGES;
}

// ---------------- bucket sort (two-pass, write-amplification-free) --------------------------
__global__ __launch_bounds__(256) void k_binit(const unsigned int* __restrict__ row_start,
                                               unsigned int* __restrict__ bucket_cursor) {
    int b = blockIdx.x * 256 + threadIdx.x;
    if (b < NBUCK) bucket_cursor[b] = row_start[b << 8];
}

__global__ __launch_bounds__(256) void k_bucket1(const int* __restrict__ esrc,
                                                 const int* __restrict__ edst,
                                                 const float* __restrict__ evalv,
                                                 unsigned int* __restrict__ bucket_cursor,
                                                 uint2* __restrict__ coarse,
                                                 unsigned char* __restrict__ coarse_dl) {
    __shared__ unsigned int hist[NBUCK];
    __shared__ unsigned int gbase[NBUCK];
    __shared__ unsigned int lcnt[NBUCK];
    int tid = threadIdx.x;
    int e0 = blockIdx.x * 8192;
    for (int i = tid; i < NBUCK; i += 256) { hist[i] = 0u; lcnt[i] = 0u; }
    __syncthreads();
    #pragma unroll 4
    for (int k = 0; k < 32; ++k) {
        int e = e0 + k * 256 + tid;
        if (e < N_EDGES) atomicAdd(&hist[((unsigned)edst[e]) >> 8], 1u);
    }
    __syncthreads();
    for (int b = tid; b < NBUCK; b += 256) {
        unsigned int h = hist[b];
        gbase[b] = h ? atomicAdd(&bucket_cursor[b], h) : 0u;
    }
    __syncthreads();
    #pragma unroll 4
    for (int k = 0; k < 32; ++k) {
        int e = e0 + k * 256 + tid;
        if (e < N_EDGES) {
            unsigned int d = (unsigned)edst[e];
            unsigned int b = d >> 8;
            unsigned int r = atomicAdd(&lcnt[b], 1u);
            unsigned int p = gbase[b] + r;
            uint2 ev;
            ev.x = (unsigned int)esrc[e];
            ev.y = __float_as_uint(evalv[e]);
            coarse[p] = ev;
            coarse_dl[p] = (unsigned char)(d & 255u);
        }
    }
}

__global__ __launch_bounds__(256) void k_bucket2(const unsigned int* __restrict__ row_start,
                                                 const uint2* __restrict__ coarse,
                                                 const unsigned char* __restrict__ coarse_dl,
                                                 unsigned int* __restrict__ cursor,
                                                 uint2* __restrict__ edge_sorted) {
    int b = blockIdx.x;
    unsigned int bs = row_start[b << 8];
    unsigned int be = (b == NBUCK - 1) ? N_EDGES : row_start[(b + 1) << 8];
    unsigned int nbase = (unsigned)b << 8;
    for (unsigned int i = bs + threadIdx.x; i < be; i += 256) {
        uint2 ev = coarse[i];
        unsigned int d = nbase | (unsigned int)coarse_dl[i];
        unsigned int p = atomicAdd(&cursor[d], 1u);
        edge_sorted[p] = ev;
    }
}

// ---------------- fuse1: gather1 + gemm1 fused. 8 nodes/block. ------------------------------
__global__ __launch_bounds__(256) void k_fuse1(const unsigned int* __restrict__ row_start,
                                               const uint2* __restrict__ edge_sorted,
                                               const float* __restrict__ X,
                                               const float* __restrict__ Wb,
                                               unsigned short* __restrict__ hidden) {
    __shared__ float Wb_s[4096];      // 16 KB
    __shared__ float s1r[8 * 33];     // gathered rows, stride-33
    int tid = threadIdx.x;
    for (int i = tid; i < 1024; i += 256)
        ((float4*)Wb_s)[i] = ((const float4*)Wb)[i];

    int lane = tid & 31;
    int nd = tid >> 5;
    int n = blockIdx.x * 8 + nd;
    unsigned int i = row_start[n], e = row_start[n + 1];
    float a0 = 0.f, a1 = 0.f, a2 = 0.f, a3 = 0.f;
    for (; i + 4 <= e; i += 4) {
        uint2 ea = edge_sorted[i + 0], eb = edge_sorted[i + 1];
        uint2 ec = edge_sorted[i + 2], ed = edge_sorted[i + 3];
        float xa = X[(size_t)ea.x * 32 + lane];
        float xb = X[(size_t)eb.x * 32 + lane];
        float xc = X[(size_t)ec.x * 32 + lane];
        float xd = X[(size_t)ed.x * 32 + lane];
        a0 += __uint_as_float(ea.y) * xa;
        a1 += __uint_as_float(eb.y) * xb;
        a2 += __uint_as_float(ec.y) * xc;
        a3 += __uint_as_float(ed.y) * xd;
    }
    for (; i < e; ++i) {
        uint2 ea = edge_sorted[i];
        a0 += __uint_as_float(ea.y) * X[(size_t)ea.x * 32 + lane];
    }
    s1r[nd * 33 + lane] = (a0 + a1) + (a2 + a3);
    __syncthreads();

    int q = lane * 4;
    float4 acc = {0.f, 0.f, 0.f, 0.f};
    #pragma unroll
    for (int k = 0; k < 32; ++k) {
        float v = s1r[nd * 33 + k];
        float4 w = *(const float4*)&Wb_s[k * 128 + q];
        acc.x += v * w.x; acc.y += v * w.y; acc.z += v * w.z; acc.w += v * w.w;
    }
    ushort4 o;
    o.x = f2us(fmaxf(acc.x, 0.f)); o.y = f2us(fmaxf(acc.y, 0.f));
    o.z = f2us(fmaxf(acc.z, 0.f)); o.w = f2us(fmaxf(acc.w, 0.f));
    *(ushort4*)&hidden[(size_t)n * 128 + q] = o;
}

// ---------------- gather2: S2[n][0:128] (bf16) = sum_e val*hidden[src]  (no LDS, unroll x4) ---
__global__ __launch_bounds__(256) void k_gather2(const unsigned int* __restrict__ row_start,
                                                 const uint2* __restrict__ edge_sorted,
                                                 const unsigned short* __restrict__ hidden,
                                                 unsigned short* __restrict__ S2) {
    int lane = threadIdx.x & 31;
    int n = blockIdx.x * 8 + (threadIdx.x >> 5);
    unsigned int i = row_start[n], e = row_start[n + 1];
    float4 A0 = {0, 0, 0, 0}, A1 = {0, 0, 0, 0}, A2 = {0, 0, 0, 0}, A3 = {0, 0, 0, 0};
    for (; i + 4 <= e; i += 4) {
        uint2 ea = edge_sorted[i + 0], eb = edge_sorted[i + 1];
        uint2 ec = edge_sorted[i + 2], ed = edge_sorted[i + 3];
        ushort4 ha = *(const ushort4*)&hidden[(size_t)ea.x * 128 + lane * 4];
        ushort4 hb = *(const ushort4*)&hidden[(size_t)eb.x * 128 + lane * 4];
        ushort4 hc = *(const ushort4*)&hidden[(size_t)ec.x * 128 + lane * 4];
        ushort4 hd = *(const ushort4*)&hidden[(size_t)ed.x * 128 + lane * 4];
        float va = __uint_as_float(ea.y), vb = __uint_as_float(eb.y);
        float vc = __uint_as_float(ec.y), vd = __uint_as_float(ed.y);
        A0.x += va * us2f(ha.x); A0.y += va * us2f(ha.y); A0.z += va * us2f(ha.z); A0.w += va * us2f(ha.w);
        A1.x += vb * us2f(hb.x); A1.y += vb * us2f(hb.y); A1.z += vb * us2f(hb.z); A1.w += vb * us2f(hb.w);
        A2.x += vc * us2f(hc.x); A2.y += vc * us2f(hc.y); A2.z += vc * us2f(hc.z); A2.w += vc * us2f(hc.w);
        A3.x += vd * us2f(hd.x); A3.y += vd * us2f(hd.y); A3.z += vd * us2f(hd.z); A3.w += vd * us2f(hd.w);
    }
    for (; i < e; ++i) {
        uint2 ea = edge_sorted[i];
        float v = __uint_as_float(ea.y);
        ushort4 h = *(const ushort4*)&hidden[(size_t)ea.x * 128 + lane * 4];
        A0.x += v * us2f(h.x); A0.y += v * us2f(h.y); A0.z += v * us2f(h.z); A0.w += v * us2f(h.w);
    }
    float4 acc;
    acc.x = (A0.x + A1.x) + (A2.x + A3.x);
    acc.y = (A0.y + A1.y) + (A2.y + A3.y);
    acc.z = (A0.z + A1.z) + (A2.z + A3.z);
    acc.w = (A0.w + A1.w) + (A2.w + A3.w);
    ushort4 o;
    o.x = f2us(acc.x); o.y = f2us(acc.y); o.z = f2us(acc.z); o.w = f2us(acc.w);
    *(ushort4*)&S2[(size_t)n * 128 + lane * 4] = o;
}

// ---------------- gemm2: mt4[c][n][d] (ushort4 per (c,n)) = (S2 @ Wcomb), [32n x 64j]/block --
__global__ __launch_bounds__(256) void k_gemm2(const unsigned short* __restrict__ S2,
                                               const float* __restrict__ Wc,
                                               unsigned short* __restrict__ mt4) {
    __shared__ float Wc_s[128 * 64];
    __shared__ float S2s[32 * 132];
    __shared__ unsigned short Tt[64 * 40];
    int tid = threadIdx.x;
    int rb = blockIdx.x >> 1;
    int j0 = (blockIdx.x & 1) * 64;
    int n0 = rb * 32;
    for (int idx = tid; idx < 2048; idx += 256) {
        int k = idx >> 4, jq = idx & 15;
        *(float4*)&Wc_s[k * 64 + jq * 4] = *(const float4*)&Wc[k * 128 + j0 + jq * 4];
    }
    for (int idx = tid; idx < 1024; idx += 256) {
        int r = idx >> 5, kq = idx & 31;
        ushort4 h = *(const ushort4*)&S2[(size_t)(n0 + r) * 128 + kq * 4];
        float4 f = {us2f(h.x), us2f(h.y), us2f(h.z), us2f(h.w)};
        *(float4*)&S2s[r * 132 + kq * 4] = f;
    }
    __syncthreads();
    int q = (tid & 15) * 4;
    int r0 = tid >> 4;
    float4 a0 = {0, 0, 0, 0}, a1 = {0, 0, 0, 0};
    for (int k4 = 0; k4 < 128; k4 += 4) {
        float4 s0 = *(const float4*)&S2s[r0 * 132 + k4];
        float4 s1 = *(const float4*)&S2s[(r0 + 16) * 132 + k4];
        #pragma unroll
        for (int kk = 0; kk < 4; ++kk) {
            float v0 = (&s0.x)[kk];
            float v1 = (&s1.x)[kk];
            float4 w = *(const float4*)&Wc_s[(k4 + kk) * 64 + q];
            a0.x += v0 * w.x; a0.y += v0 * w.y; a0.z += v0 * w.z; a0.w += v0 * w.w;
            a1.x += v1 * w.x; a1.y += v1 * w.y; a1.z += v1 * w.z; a1.w += v1 * w.w;
        }
    }
    #pragma unroll
    for (int c = 0; c < 4; ++c) {
        Tt[(q + c) * 40 + r0]      = f2us((&a0.x)[c]);
        Tt[(q + c) * 40 + r0 + 16] = f2us((&a1.x)[c]);
    }
    __syncthreads();
    int cc = tid >> 4;              // 0..15
    int r  = (tid & 15) * 2;        // node pair
    int cg = (j0 >> 2) + cc;        // global concept
    #pragma unroll
    for (int rr = 0; rr < 2; ++rr) {
        ushort4 o;
        o.x = Tt[(cc * 4 + 0) * 40 + r + rr];
        o.y = Tt[(cc * 4 + 1) * 40 + r + rr];
        o.z = Tt[(cc * 4 + 2) * 40 + r + rr];
        o.w = Tt[(cc * 4 + 3) * 40 + r + rr];
        *(ushort4*)&mt4[((size_t)cg * N_NODES + n0 + r + rr) * 4] = o;
    }
}

// ---------------- noisew: noiseW[n][32] = sqrt(lambda)*noise[n] @ Wrec + brec ---------------
__global__ __launch_bounds__(256) void k_noisew(const float* __restrict__ noise,
                                                const float* __restrict__ Wrec,
                                                const float* __restrict__ brec,
                                                float* __restrict__ noiseW) {
    __shared__ float Wr[4096];        // [k][o] 128x32 (16 KB)
    __shared__ float Ns[64 * 132];    // scaled noise rows (33.8 KB)
    __shared__ float brs[32];
    int tid = threadIdx.x;
    int n0 = blockIdx.x * 64;
    const float SQ = 0.03162277660168379f;
    for (int i = tid; i < 1024; i += 256)
        ((float4*)Wr)[i] = ((const float4*)Wrec)[i];
    if (tid < 32) brs[tid] = brec[tid];
    for (int i = tid; i < 1024; i += 256) {
        int row = i >> 4, u8 = i & 15;
        int n = n0 + row;
        float4 f0, f1;
        if (n < N_NODES) {
            f0 = ((const float4*)(noise + (size_t)n * 128))[u8 * 2];
            f1 = ((const float4*)(noise + (size_t)n * 128))[u8 * 2 + 1];
        } else {
            f0 = make_float4(0.f, 0.f, 0.f, 0.f);
            f1 = f0;
        }
        *(float4*)&Ns[row * 132 + u8 * 8]     = make_float4(SQ * f0.x, SQ * f0.y, SQ * f0.z, SQ * f0.w);
        *(float4*)&Ns[row * 132 + u8 * 8 + 4] = make_float4(SQ * f1.x, SQ * f1.y, SQ * f1.z, SQ * f1.w);
    }
    __syncthreads();
    int r = tid >> 2, q = (tid & 3) * 8;
    float4 acc0 = {0, 0, 0, 0}, acc1 = {0, 0, 0, 0};
    for (int k = 0; k < 128; ++k) {
        float nv = Ns[r * 132 + k];
        float4 w0 = *(const float4*)&Wr[k * 32 + q];
        float4 w1 = *(const float4*)&Wr[k * 32 + q + 4];
        acc0.x += nv * w0.x; acc0.y += nv * w0.y; acc0.z += nv * w0.z; acc0.w += nv * w0.w;
        acc1.x += nv * w1.x; acc1.y += nv * w1.y; acc1.z += nv * w1.z; acc1.w += nv * w1.w;
    }
    int n = n0 + r;
    if (n < N_NODES) {
        acc0.x += brs[q];     acc0.y += brs[q + 1]; acc0.z += brs[q + 2]; acc0.w += brs[q + 3];
        acc1.x += brs[q + 4]; acc1.y += brs[q + 5]; acc1.z += brs[q + 6]; acc1.w += brs[q + 7];
        ((float4*)(noiseW + (size_t)n * 32 + q))[0] = acc0;
        ((float4*)(noiseW + (size_t)n * 32 + q + 4))[0] = acc1;
    }
}

// ---------------- nodez: 512 thr = 8 waves, wave w = concept group [4w,4w+4) x 64 nodes. -----
// 2x the wave supply of the 4-split (12.5K waves, ~12/SIMD) and LDS cut 52.2->8.4 KB
// (4 blocks/CU wave-capped). Weight delivery keeps the round-4-verified structure: separate
// __restrict__ arrays, wave-uniform readfirstlane concept base -> scalar loads. Combine via
// LDS ds_add_f32 into a 64x33 accumulator (proven correct in round 6; stride-33 = free alias).
__global__ __launch_bounds__(512) void k_nodez(const unsigned short* __restrict__ mt4,
                                               const float* __restrict__ Wz1,
                                               const float* __restrict__ bz1,
                                               const float* __restrict__ Wz2,
                                               const float* __restrict__ bz2,
                                               const float* __restrict__ Wrec,
                                               const float* __restrict__ noiseW,
                                               float* __restrict__ out) {
    __shared__ float scr[64 * 33];                 // 8.4 KB accumulator
    int tid = threadIdx.x;
    for (int i = tid; i < 64 * 33; i += 512) scr[i] = 0.f;
    __syncthreads();

    int lt = tid & 63;                             // node slot (one wave = one group)
    int gq = tid >> 6;                             // concept group 0..7
    int c0 = __builtin_amdgcn_readfirstlane(gq * 4);
    int n = blockIdx.x * 64 + lt;
    bool ok = n < N_NODES;
    int m = ok ? n : (N_NODES - 1);

    const float4* W1 = (const float4*)Wz1;   // [c*32 + d*8 + g4]
    const float4* B1 = (const float4*)bz1;   // [c*8 + g4]
    const float4* W2 = (const float4*)Wz2;   // [c*32 + g]
    const float4* B2 = (const float4*)bz2;   // [c]
    const float4* WR = (const float4*)Wrec;  // [(c*4+d)*8 + o4]

    float4 o0 = {0,0,0,0}, o1 = {0,0,0,0}, o2 = {0,0,0,0}, o3 = {0,0,0,0};
    float4 o4v = {0,0,0,0}, o5 = {0,0,0,0}, o6 = {0,0,0,0}, o7 = {0,0,0,0};

    ushort4 mz = *(const ushort4*)&mt4[((size_t)c0 * N_NODES + m) * 4];

    for (int cc = 0; cc < 4; ++cc) {
        int c = c0 + cc;
        int cn = (cc < 3) ? (c + 1) : c;
        ushort4 nmz = *(const ushort4*)&mt4[((size_t)cn * N_NODES + m) * 4];
        float a0 = us2f(mz.x), a1 = us2f(mz.y), a2 = us2f(mz.z), a3 = us2f(mz.w);

        float4 zb = B2[c];
        float4 z = zb;
        #pragma unroll
        for (int g4 = 0; g4 < 8; ++g4) {
            float4 w0 = W1[c * 32 + g4];
            float4 w1 = W1[c * 32 + 8 + g4];
            float4 w2 = W1[c * 32 + 16 + g4];
            float4 w3 = W1[c * 32 + 24 + g4];
            float4 bb = B1[c * 8 + g4];
            float4 v;
            v.x = bb.x + a0 * w0.x + a1 * w1.x + a2 * w2.x + a3 * w3.x;
            v.y = bb.y + a0 * w0.y + a1 * w1.y + a2 * w2.y + a3 * w3.y;
            v.z = bb.z + a0 * w0.z + a1 * w1.z + a2 * w2.z + a3 * w3.z;
            v.w = bb.w + a0 * w0.w + a1 * w1.w + a2 * w2.w + a3 * w3.w;
            v.x = elu_fast(v.x); v.y = elu_fast(v.y); v.z = elu_fast(v.z); v.w = elu_fast(v.w);
            float4 u0 = W2[c * 32 + g4 * 4 + 0];
            float4 u1 = W2[c * 32 + g4 * 4 + 1];
            float4 u2 = W2[c * 32 + g4 * 4 + 2];
            float4 u3 = W2[c * 32 + g4 * 4 + 3];
            z.x += v.x * u0.x + v.y * u1.x + v.z * u2.x + v.w * u3.x;
            z.y += v.x * u0.y + v.y * u1.y + v.z * u2.y + v.w * u3.y;
            z.z += v.x * u0.z + v.y * u1.z + v.z * u2.z + v.w * u3.z;
            z.w += v.x * u0.w + v.y * u1.w + v.z * u2.w + v.w * u3.w;
        }
        #pragma unroll
        for (int d = 0; d < 4; ++d) {
            float zv = (&z.x)[d];
            const float4* wr = &WR[(c * 4 + d) * 8];
            float4 r0 = wr[0], r1 = wr[1], r2 = wr[2], r3 = wr[3];
            float4 r4 = wr[4], r5 = wr[5], r6 = wr[6], r7 = wr[7];
            o0.x += zv * r0.x; o0.y += zv * r0.y; o0.z += zv * r0.z; o0.w += zv * r0.w;
            o1.x += zv * r1.x; o1.y += zv * r1.y; o1.z += zv * r1.z; o1.w += zv * r1.w;
            o2.x += zv * r2.x; o2.y += zv * r2.y; o2.z += zv * r2.z; o2.w += zv * r2.w;
            o3.x += zv * r3.x; o3.y += zv * r3.y; o3.z += zv * r3.z; o3.w += zv * r3.w;
            o4v.x += zv * r4.x; o4v.y += zv * r4.y; o4v.z += zv * r4.z; o4v.w += zv * r4.w;
            o5.x += zv * r5.x; o5.y += zv * r5.y; o5.z += zv * r5.z; o5.w += zv * r5.w;
            o6.x += zv * r6.x; o6.y += zv * r6.y; o6.z += zv * r6.z; o6.w += zv * r6.w;
            o7.x += zv * r7.x; o7.y += zv * r7.y; o7.z += zv * r7.z; o7.w += zv * r7.w;
        }
        mz = nmz;
    }

    // ---- combine: groups 1..7 ds_add into scr; group 0 keeps its partials in regs ----
    if (gq != 0) {
        float* p = &scr[lt * 33];
        atomicAdd(&p[0],  o0.x);  atomicAdd(&p[1],  o0.y);  atomicAdd(&p[2],  o0.z);  atomicAdd(&p[3],  o0.w);
        atomicAdd(&p[4],  o1.x);  atomicAdd(&p[5],  o1.y);  atomicAdd(&p[6],  o1.z);  atomicAdd(&p[7],  o1.w);
        atomicAdd(&p[8],  o2.x);  atomicAdd(&p[9],  o2.y);  atomicAdd(&p[10], o2.z);  atomicAdd(&p[11], o2.w);
        atomicAdd(&p[12], o3.x);  atomicAdd(&p[13], o3.y);  atomicAdd(&p[14], o3.z);  atomicAdd(&p[15], o3.w);
        atomicAdd(&p[16], o4v.x); atomicAdd(&p[17], o4v.y); atomicAdd(&p[18], o4v.z); atomicAdd(&p[19], o4v.w);
        atomicAdd(&p[20], o5.x);  atomicAdd(&p[21], o5.y);  atomicAdd(&p[22], o5.z);  atomicAdd(&p[23], o5.w);
        atomicAdd(&p[24], o6.x);  atomicAdd(&p[25], o6.y);  atomicAdd(&p[26], o6.z);  atomicAdd(&p[27], o6.w);
        atomicAdd(&p[28], o7.x);  atomicAdd(&p[29], o7.y);  atomicAdd(&p[30], o7.z);  atomicAdd(&p[31], o7.w);
    }
    __syncthreads();
    if (gq == 0 && ok) {
        const float* p = &scr[lt * 33];
        const float4* nw = (const float4*)(noiseW + (size_t)n * 32);
        float4* po = (float4*)(out + (size_t)n * 32);
        float4 w, t;
        w = nw[0];
        t.x = o0.x + p[0] + w.x;   t.y = o0.y + p[1] + w.y;
        t.z = o0.z + p[2] + w.z;   t.w = o0.w + p[3] + w.w;   po[0] = t;
        w = nw[1];
        t.x = o1.x + p[4] + w.x;   t.y = o1.y + p[5] + w.y;
        t.z = o1.z + p[6] + w.z;   t.w = o1.w + p[7] + w.w;   po[1] = t;
        w = nw[2];
        t.x = o2.x + p[8] + w.x;   t.y = o2.y + p[9] + w.y;
        t.z = o2.z + p[10] + w.z;  t.w = o2.w + p[11] + w.w;  po[2] = t;
        w = nw[3];
        t.x = o3.x + p[12] + w.x;  t.y = o3.y + p[13] + w.y;
        t.z = o3.z + p[14] + w.z;  t.w = o3.w + p[15] + w.w;  po[3] = t;
        w = nw[4];
        t.x = o4v.x + p[16] + w.x; t.y = o4v.y + p[17] + w.y;
        t.z = o4v.z + p[18] + w.z; t.w = o4v.w + p[19] + w.w; po[4] = t;
        w = nw[5];
        t.x = o5.x + p[20] + w.x;  t.y = o5.y + p[21] + w.y;
        t.z = o5.z + p[22] + w.z;  t.w = o5.w + p[23] + w.w;  po[5] = t;
        w = nw[6];
        t.x = o6.x + p[24] + w.x;  t.y = o6.y + p[25] + w.y;
        t.z = o6.z + p[26] + w.z;  t.w = o6.w + p[27] + w.w;  po[6] = t;
        w = nw[7];
        t.x = o7.x + p[28] + w.x;  t.y = o7.y + p[29] + w.y;
        t.z = o7.z + p[30] + w.z;  t.w = o7.w + p[31] + w.w;  po[7] = t;
    }
}

// ---------------- label head: pred = MLP_c(A^T@label), one lane per node ---------------------
__global__ __launch_bounds__(256) void k_label(const float* __restrict__ label,
                                               const float* __restrict__ A,
                                               const float* __restrict__ Wl1,
                                               const float* __restrict__ bl1,
                                               const float* __restrict__ Wl2,
                                               const float* __restrict__ bl2,
                                               float* __restrict__ out) {
    __shared__ float As[1024], Wl1s[1024], bl1s[1024], Wl2s[1024], bl2s[32];
    int tid = threadIdx.x;
    for (int i = tid; i < 1024; i += 256) {
        As[i] = A[i];
        Wl1s[i] = Wl1[i];
        bl1s[i] = bl1[i];
        Wl2s[i] = Wl2[i];
    }
    if (tid < 32) bl2s[tid] = bl2[tid];
    __syncthreads();

    int n = blockIdx.x * 256 + tid;
    bool ok = n < N_NODES;
    int nn = ok ? n : (N_NODES - 1);

    float lab[32];
    #pragma unroll
    for (int q = 0; q < 8; ++q) {
        float4 lv = ((const float4*)(label + (size_t)nn * 32))[q];
        lab[q * 4 + 0] = lv.x; lab[q * 4 + 1] = lv.y;
        lab[q * 4 + 2] = lv.z; lab[q * 4 + 3] = lv.w;
    }
    float pred[32];
    for (int c = 0; c < 32; ++c) {
        float ml = 0.f;
        #pragma unroll
        for (int k = 0; k < 32; ++k) ml += As[k * 32 + c] * lab[k];
        float p = bl2s[c];
        #pragma unroll
        for (int g = 0; g < 32; ++g) {
            float h = elu_fast(ml * Wl1s[c * 32 + g] + bl1s[c * 32 + g]);
            p += h * Wl2s[c * 32 + g];
        }
        pred[c] = p;
    }
    if (ok) {
        #pragma unroll
        for (int q = 0; q < 8; ++q) {
            float4 v = {pred[q * 4 + 0], pred[q * 4 + 1], pred[q * 4 + 2], pred[q * 4 + 3]};
            ((float4*)(out + (size_t)N_NODES * 32 + (size_t)n * 32))[q] = v;
        }
    }
}

extern "C" void kernel_launch(void* const* d_in, const int* in_sizes, int n_in,
                              void* d_out, int out_size, void* d_ws, size_t ws_size,
                              hipStream_t stream) {
    const float* X      = (const float*)d_in[0];
    const float* label  = (const float*)d_in[1];
    const float* evalv  = (const float*)d_in[2];
    const float* noise  = (const float*)d_in[3];
    const float* W_base = (const float*)d_in[4];
    const float* W_mean = (const float*)d_in[5];
    // d_in[6] = W_logstd : dead code in the reference
    const float* A      = (const float*)d_in[7];
    const float* Wz1    = (const float*)d_in[8];
    const float* bz1    = (const float*)d_in[9];
    const float* Wz2    = (const float*)d_in[10];
    const float* bz2    = (const float*)d_in[11];
    const float* Wl1    = (const float*)d_in[12];
    const float* bl1    = (const float*)d_in[13];
    const float* Wl2    = (const float*)d_in[14];
    const float* bl2    = (const float*)d_in[15];
    const float* Wrec   = (const float*)d_in[16];
    const float* brec   = (const float*)d_in[17];
    const int* esrc = (const int*)d_in[18];
    const int* edst = (const int*)d_in[19];
    float* out = (float*)d_out;

    char* ws = (char*)d_ws;
    // Layout (~65.3 MB total; <= proven-safe 73.3 MB):
    float*          Wcomb       = (float*)(ws);                        // 64 KB
    float*          MmT         = (float*)(ws + 65536);                // 4 KB
    unsigned int*   blk_sums    = (unsigned int*)(ws + 69632);         // 1 KB
    unsigned int*   deg         = (unsigned int*)(ws + 70656);         // padded 100352 u32
    unsigned int*   bucket_cursor = (unsigned int*)(ws + 70656);       // overlays deg (dead after scanA)
    unsigned int*   row_start   = (unsigned int*)(ws + 472064);        // N+1 u32
    unsigned int*   cursor      = (unsigned int*)(ws + 873984);        // N u32
    uint2*          edge_sorted = (uint2*)(ws + 1273984);              // 12.8 MB
    // slot A (25.6 MB): {coarse+coarse_dl scratch during bucket sort} -> hidden (bf16) -> mt4
    uint2*          coarse      = (uint2*)(ws + 14073984);             // 12.8 MB (dead before fuse1)
    unsigned char*  coarse_dl   = (unsigned char*)(ws + 26873984);     // 1.6 MB  (dead before fuse1)
    unsigned short* hidden      = (unsigned short*)(ws + 14073984);
    unsigned short* mt4         = (unsigned short*)(ws + 14073984);
    // slot B (25.6 MB): S2 (bf16) -> noiseW (f32, written after gemm2 consumes S2)
    unsigned short* S2          = (unsigned short*)(ws + 39673984);
    float*          noiseW      = (float*)(ws + 39673984);

    hipMemsetAsync(deg, 0, 100352 * sizeof(unsigned int), stream);
    k_inv<<<1, 64, 0, stream>>>(A, MmT);
    k_fold<<<16, 256, 0, stream>>>(MmT, W_mean, Wcomb);
    k_hist<<<N_EDGES / 256, 256, 0, stream>>>(edst, deg);
    k_scanA<<<98, 256, 0, stream>>>(deg, row_start, blk_sums);
    k_scanB<<<1, 128, 0, stream>>>(blk_sums);
    k_scanC<<<98, 256, 0, stream>>>(row_start, cursor, blk_sums);
    k_binit<<<2, 256, 0, stream>>>(row_start, bucket_cursor);
    k_bucket1<<<(N_EDGES + 8191) / 8192, 256, 0, stream>>>(esrc, edst, evalv,
                                                           bucket_cursor, coarse, coarse_dl);
    k_bucket2<<<NBUCK, 256, 0, stream>>>(row_start, coarse, coarse_dl, cursor, edge_sorted);
    k_fuse1<<<N_NODES / 8, 256, 0, stream>>>(row_start, edge_sorted, X, W_base, hidden);
    k_gather2<<<N_NODES / 8, 256, 0, stream>>>(row_start, edge_sorted, hidden, S2);
    k_gemm2<<<(N_NODES / 32) * 2, 256, 0, stream>>>(S2, Wcomb, mt4);
    k_noisew<<<(N_NODES + 63) / 64, 256, 0, stream>>>(noise, Wrec, brec, noiseW);
    k_nodez<<<(N_NODES + 63) / 64, 512, 0, stream>>>(mt4,
                                                     Wz1, bz1, Wz2, bz2,
                                                     Wrec, noiseW, out);
    k_label<<<(N_NODES + 255) / 256, 256, 0, stream>>>(label, A, Wl1, bl1, Wl2, bl2, out);
}

// Round 9
// 679.335 us; speedup vs baseline: 1.2361x; 1.2361x over previous
//
#include <hip/hip_runtime.h>
#include <hip/hip_bf16.h>

#define N_NODES 100000
#define N_EDGES 1600000
#define NBUCK   391          // ceil(100000/256) node-buckets of 256
#define EHIST_G 196          // ceil(1600000/8192) 8192-edge tiles

static __device__ __forceinline__ float us2f(unsigned short u) {
    union { unsigned int i; float f; } cv; cv.i = ((unsigned int)u) << 16; return cv.f;
}
static __device__ __forceinline__ unsigned short f2us(float f) {
    __hip_bfloat16 b = __float2bfloat16(f);
    union { __hip_bfloat16 b; unsigned short u; } cv; cv.b = b; return cv.u;
}
static __device__ __forceinline__ float elu_fast(float v) {
    return v > 0.f ? v : (__expf(v) - 1.0f);
}

// ---------------- inv: single-wave Gauss-Jordan; outputs MmT[j*32+c] = (A^T (I-A^T)^{-1})[c][j]
__global__ __launch_bounds__(64) void k_inv(const float* __restrict__ A,
                                            float* __restrict__ MmT) {
    __shared__ float Af[1024];
    __shared__ float aug[32 * 65];
    __shared__ float fac[32];
    __shared__ float pv_s;
    int t = threadIdx.x;
    for (int i = t; i < 1024; i += 64) Af[i] = A[i];
    __syncthreads();
    for (int i = t; i < 2048; i += 64) {
        int r = i >> 6, c = i & 63;
        float v;
        if (c < 32) v = (r == c ? 1.0f : 0.0f) - Af[c * 32 + r];
        else        v = ((c - 32) == r ? 1.0f : 0.0f);
        aug[r * 65 + c] = v;
    }
    __syncthreads();
    for (int k = 0; k < 32; ++k) {
        if (t == 0) pv_s = 1.0f / aug[k * 65 + k];
        __syncthreads();
        aug[k * 65 + t] *= pv_s;
        __syncthreads();
        if (t < 32) fac[t] = aug[t * 65 + k];
        __syncthreads();
        #pragma unroll 4
        for (int i = t; i < 2048; i += 64) {
            int r = i >> 6, c = i & 63;
            if (r != k) aug[r * 65 + c] -= fac[r] * aug[k * 65 + c];
        }
        __syncthreads();
    }
    for (int i = t; i < 1024; i += 64) {
        int j = i >> 5, c = i & 31;
        float s = 0.f;
        #pragma unroll
        for (int k = 0; k < 32; ++k) s += Af[k * 32 + c] * aug[k * 65 + 32 + j];
        MmT[i] = s;
    }
}

// ---------------- fold: Wcomb[h][c*4+d] = sum_j Mm[c][j]*Wm[h*128+j*4+d]  (16 blocks) --------
__global__ __launch_bounds__(256) void k_fold(const float* __restrict__ MmT,
                                              const float* __restrict__ Wm,
                                              float* __restrict__ Wcomb) {
    __shared__ float MmTs[1024];
    int tid = threadIdx.x;
    for (int i = tid; i < 1024; i += 256) MmTs[i] = MmT[i];
    __syncthreads();
    int o = blockIdx.x * 256 + tid;
    int h = o >> 5, c = o & 31;
    float4 s = {0.f, 0.f, 0.f, 0.f};
    #pragma unroll
    for (int j = 0; j < 32; ++j) {
        float m = MmTs[j * 32 + c];
        float4 w = ((const float4*)Wm)[h * 32 + j];
        s.x += m * w.x; s.y += m * w.y; s.z += m * w.z; s.w += m * w.w;
    }
    ((float4*)Wcomb)[o] = s;
}

// ---------------- bucket-level histogram: bucket_deg[b] = #edges with dst in bucket b --------
// Replaces k_hist's 1.6M random global atomics with LDS hist + 76K bucket-granular adds.
__global__ __launch_bounds__(256) void k_bhist(const int* __restrict__ edst,
                                               unsigned int* __restrict__ bucket_deg) {
    __shared__ unsigned int h[NBUCK];
    int tid = threadIdx.x;
    int e0 = blockIdx.x * 8192;
    for (int i = tid; i < NBUCK; i += 256) h[i] = 0u;
    __syncthreads();
    #pragma unroll 4
    for (int k = 0; k < 32; ++k) {
        int e = e0 + k * 256 + tid;
        if (e < N_EDGES) atomicAdd(&h[((unsigned)edst[e]) >> 8], 1u);
    }
    __syncthreads();
    for (int b = tid; b < NBUCK; b += 256) {
        unsigned int v = h[b];
        if (v) atomicAdd(&bucket_deg[b], v);
    }
}

// ---------------- bucket scan: bucket_start = exclusive scan(bucket_deg); cursor copy --------
__global__ __launch_bounds__(512) void k_bscan(const unsigned int* __restrict__ bucket_deg,
                                               unsigned int* __restrict__ bucket_start,
                                               unsigned int* __restrict__ bucket_cursor) {
    __shared__ unsigned int s[512];
    int tid = threadIdx.x;
    unsigned int v = (tid < NBUCK) ? bucket_deg[tid] : 0u;
    s[tid] = v;
    __syncthreads();
    for (int off = 1; off < 512; off <<= 1) {
        unsigned int x = (tid >= off) ? s[tid - off] : 0u;
        __syncthreads();
        s[tid] += x;
        __syncthreads();
    }
    if (tid < NBUCK) {
        unsigned int excl = s[tid] - v;
        bucket_start[tid] = excl;
        bucket_cursor[tid] = excl;
    }
    if (tid == 0) bucket_start[NBUCK] = N_EDGES;
}

// ---------------- bucket1: coarse scatter into 391 buckets (unchanged structure) -------------
__global__ __launch_bounds__(256) void k_bucket1(const int* __restrict__ esrc,
                                                 const int* __restrict__ edst,
                                                 const float* __restrict__ evalv,
                                                 unsigned int* __restrict__ bucket_cursor,
                                                 uint2* __restrict__ coarse,
                                                 unsigned char* __restrict__ coarse_dl) {
    __shared__ unsigned int hist[NBUCK];
    __shared__ unsigned int gbase[NBUCK];
    __shared__ unsigned int lcnt[NBUCK];
    int tid = threadIdx.x;
    int e0 = blockIdx.x * 8192;
    for (int i = tid; i < NBUCK; i += 256) { hist[i] = 0u; lcnt[i] = 0u; }
    __syncthreads();
    #pragma unroll 4
    for (int k = 0; k < 32; ++k) {
        int e = e0 + k * 256 + tid;
        if (e < N_EDGES) atomicAdd(&hist[((unsigned)edst[e]) >> 8], 1u);
    }
    __syncthreads();
    for (int b = tid; b < NBUCK; b += 256) {
        unsigned int h = hist[b];
        gbase[b] = h ? atomicAdd(&bucket_cursor[b], h) : 0u;
    }
    __syncthreads();
    #pragma unroll 4
    for (int k = 0; k < 32; ++k) {
        int e = e0 + k * 256 + tid;
        if (e < N_EDGES) {
            unsigned int d = (unsigned)edst[e];
            unsigned int b = d >> 8;
            unsigned int r = atomicAdd(&lcnt[b], 1u);
            unsigned int p = gbase[b] + r;
            uint2 ev;
            ev.x = (unsigned int)esrc[e];
            ev.y = __float_as_uint(evalv[e]);
            coarse[p] = ev;
            coarse_dl[p] = (unsigned char)(d & 255u);
        }
    }
}

// ---------------- bucket2: per-bucket LDS hist + scan -> row_start (coalesced) + fine sort ---
// All per-node counting/cursoring in LDS; zero global atomics. Also emits row_start, replacing
// the old hist+scanA/B/C+binit global passes entirely.
__global__ __launch_bounds__(256) void k_bucket2(const unsigned int* __restrict__ bucket_start,
                                                 const uint2* __restrict__ coarse,
                                                 const unsigned char* __restrict__ coarse_dl,
                                                 unsigned int* __restrict__ row_start,
                                                 uint2* __restrict__ edge_sorted) {
    __shared__ unsigned int h[256];
    __shared__ unsigned int sc[256];
    int b = blockIdx.x;
    int tid = threadIdx.x;
    unsigned int bs = bucket_start[b];
    unsigned int be = bucket_start[b + 1];
    h[tid] = 0u;
    __syncthreads();
    for (unsigned int i = bs + tid; i < be; i += 256)
        atomicAdd(&h[coarse_dl[i]], 1u);
    __syncthreads();
    unsigned int v = h[tid];
    sc[tid] = v;
    __syncthreads();
    for (int off = 1; off < 256; off <<= 1) {
        unsigned int x = (tid >= off) ? sc[tid - off] : 0u;
        __syncthreads();
        sc[tid] += x;
        __syncthreads();
    }
    unsigned int excl = sc[tid] - v;
    int node = (b << 8) + tid;
    if (node < N_NODES) row_start[node] = bs + excl;
    if (b == 0 && tid == 0) row_start[N_NODES] = N_EDGES;
    h[tid] = excl;                 // reuse as intra-bucket cursor
    __syncthreads();
    for (unsigned int i = bs + tid; i < be; i += 256) {
        uint2 ev = coarse[i];
        unsigned int dl = coarse_dl[i];
        unsigned int r = atomicAdd(&h[dl], 1u);
        edge_sorted[bs + r] = ev;
    }
}

// ---------------- fuse1: gather1 + gemm1 fused. 8 nodes/block. ------------------------------
__global__ __launch_bounds__(256) void k_fuse1(const unsigned int* __restrict__ row_start,
                                               const uint2* __restrict__ edge_sorted,
                                               const float* __restrict__ X,
                                               const float* __restrict__ Wb,
                                               unsigned short* __restrict__ hidden) {
    __shared__ float Wb_s[4096];      // 16 KB
    __shared__ float s1r[8 * 33];     // gathered rows, stride-33
    int tid = threadIdx.x;
    for (int i = tid; i < 1024; i += 256)
        ((float4*)Wb_s)[i] = ((const float4*)Wb)[i];

    int lane = tid & 31;
    int nd = tid >> 5;
    int n = blockIdx.x * 8 + nd;
    unsigned int i = row_start[n], e = row_start[n + 1];
    float a0 = 0.f, a1 = 0.f, a2 = 0.f, a3 = 0.f;
    for (; i + 4 <= e; i += 4) {
        uint2 ea = edge_sorted[i + 0], eb = edge_sorted[i + 1];
        uint2 ec = edge_sorted[i + 2], ed = edge_sorted[i + 3];
        float xa = X[(size_t)ea.x * 32 + lane];
        float xb = X[(size_t)eb.x * 32 + lane];
        float xc = X[(size_t)ec.x * 32 + lane];
        float xd = X[(size_t)ed.x * 32 + lane];
        a0 += __uint_as_float(ea.y) * xa;
        a1 += __uint_as_float(eb.y) * xb;
        a2 += __uint_as_float(ec.y) * xc;
        a3 += __uint_as_float(ed.y) * xd;
    }
    for (; i < e; ++i) {
        uint2 ea = edge_sorted[i];
        a0 += __uint_as_float(ea.y) * X[(size_t)ea.x * 32 + lane];
    }
    s1r[nd * 33 + lane] = (a0 + a1) + (a2 + a3);
    __syncthreads();

    int q = lane * 4;
    float4 acc = {0.f, 0.f, 0.f, 0.f};
    #pragma unroll
    for (int k = 0; k < 32; ++k) {
        float v = s1r[nd * 33 + k];
        float4 w = *(const float4*)&Wb_s[k * 128 + q];
        acc.x += v * w.x; acc.y += v * w.y; acc.z += v * w.z; acc.w += v * w.w;
    }
    ushort4 o;
    o.x = f2us(fmaxf(acc.x, 0.f)); o.y = f2us(fmaxf(acc.y, 0.f));
    o.z = f2us(fmaxf(acc.z, 0.f)); o.w = f2us(fmaxf(acc.w, 0.f));
    *(ushort4*)&hidden[(size_t)n * 128 + q] = o;
}

// ---------------- gather2: S2[n][0:128] (bf16) = sum_e val*hidden[src]  (no LDS, unroll x4) ---
__global__ __launch_bounds__(256) void k_gather2(const unsigned int* __restrict__ row_start,
                                                 const uint2* __restrict__ edge_sorted,
                                                 const unsigned short* __restrict__ hidden,
                                                 unsigned short* __restrict__ S2) {
    int lane = threadIdx.x & 31;
    int n = blockIdx.x * 8 + (threadIdx.x >> 5);
    unsigned int i = row_start[n], e = row_start[n + 1];
    float4 A0 = {0, 0, 0, 0}, A1 = {0, 0, 0, 0}, A2 = {0, 0, 0, 0}, A3 = {0, 0, 0, 0};
    for (; i + 4 <= e; i += 4) {
        uint2 ea = edge_sorted[i + 0], eb = edge_sorted[i + 1];
        uint2 ec = edge_sorted[i + 2], ed = edge_sorted[i + 3];
        ushort4 ha = *(const ushort4*)&hidden[(size_t)ea.x * 128 + lane * 4];
        ushort4 hb = *(const ushort4*)&hidden[(size_t)eb.x * 128 + lane * 4];
        ushort4 hc = *(const ushort4*)&hidden[(size_t)ec.x * 128 + lane * 4];
        ushort4 hd = *(const ushort4*)&hidden[(size_t)ed.x * 128 + lane * 4];
        float va = __uint_as_float(ea.y), vb = __uint_as_float(eb.y);
        float vc = __uint_as_float(ec.y), vd = __uint_as_float(ed.y);
        A0.x += va * us2f(ha.x); A0.y += va * us2f(ha.y); A0.z += va * us2f(ha.z); A0.w += va * us2f(ha.w);
        A1.x += vb * us2f(hb.x); A1.y += vb * us2f(hb.y); A1.z += vb * us2f(hb.z); A1.w += vb * us2f(hb.w);
        A2.x += vc * us2f(hc.x); A2.y += vc * us2f(hc.y); A2.z += vc * us2f(hc.z); A2.w += vc * us2f(hc.w);
        A3.x += vd * us2f(hd.x); A3.y += vd * us2f(hd.y); A3.z += vd * us2f(hd.z); A3.w += vd * us2f(hd.w);
    }
    for (; i < e; ++i) {
        uint2 ea = edge_sorted[i];
        float v = __uint_as_float(ea.y);
        ushort4 h = *(const ushort4*)&hidden[(size_t)ea.x * 128 + lane * 4];
        A0.x += v * us2f(h.x); A0.y += v * us2f(h.y); A0.z += v * us2f(h.z); A0.w += v * us2f(h.w);
    }
    float4 acc;
    acc.x = (A0.x + A1.x) + (A2.x + A3.x);
    acc.y = (A0.y + A1.y) + (A2.y + A3.y);
    acc.z = (A0.z + A1.z) + (A2.z + A3.z);
    acc.w = (A0.w + A1.w) + (A2.w + A3.w);
    ushort4 o;
    o.x = f2us(acc.x); o.y = f2us(acc.y); o.z = f2us(acc.z); o.w = f2us(acc.w);
    *(ushort4*)&S2[(size_t)n * 128 + lane * 4] = o;
}

// ---------------- gemm2: mt4[c][n][d] (ushort4 per (c,n)) = (S2 @ Wcomb), [32n x 64j]/block --
__global__ __launch_bounds__(256) void k_gemm2(const unsigned short* __restrict__ S2,
                                               const float* __restrict__ Wc,
                                               unsigned short* __restrict__ mt4) {
    __shared__ float Wc_s[128 * 64];
    __shared__ float S2s[32 * 132];
    __shared__ unsigned short Tt[64 * 40];
    int tid = threadIdx.x;
    int rb = blockIdx.x >> 1;
    int j0 = (blockIdx.x & 1) * 64;
    int n0 = rb * 32;
    for (int idx = tid; idx < 2048; idx += 256) {
        int k = idx >> 4, jq = idx & 15;
        *(float4*)&Wc_s[k * 64 + jq * 4] = *(const float4*)&Wc[k * 128 + j0 + jq * 4];
    }
    for (int idx = tid; idx < 1024; idx += 256) {
        int r = idx >> 5, kq = idx & 31;
        ushort4 h = *(const ushort4*)&S2[(size_t)(n0 + r) * 128 + kq * 4];
        float4 f = {us2f(h.x), us2f(h.y), us2f(h.z), us2f(h.w)};
        *(float4*)&S2s[r * 132 + kq * 4] = f;
    }
    __syncthreads();
    int q = (tid & 15) * 4;
    int r0 = tid >> 4;
    float4 a0 = {0, 0, 0, 0}, a1 = {0, 0, 0, 0};
    for (int k4 = 0; k4 < 128; k4 += 4) {
        float4 s0 = *(const float4*)&S2s[r0 * 132 + k4];
        float4 s1 = *(const float4*)&S2s[(r0 + 16) * 132 + k4];
        #pragma unroll
        for (int kk = 0; kk < 4; ++kk) {
            float v0 = (&s0.x)[kk];
            float v1 = (&s1.x)[kk];
            float4 w = *(const float4*)&Wc_s[(k4 + kk) * 64 + q];
            a0.x += v0 * w.x; a0.y += v0 * w.y; a0.z += v0 * w.z; a0.w += v0 * w.w;
            a1.x += v1 * w.x; a1.y += v1 * w.y; a1.z += v1 * w.z; a1.w += v1 * w.w;
        }
    }
    #pragma unroll
    for (int c = 0; c < 4; ++c) {
        Tt[(q + c) * 40 + r0]      = f2us((&a0.x)[c]);
        Tt[(q + c) * 40 + r0 + 16] = f2us((&a1.x)[c]);
    }
    __syncthreads();
    int cc = tid >> 4;              // 0..15
    int r  = (tid & 15) * 2;        // node pair
    int cg = (j0 >> 2) + cc;        // global concept
    #pragma unroll
    for (int rr = 0; rr < 2; ++rr) {
        ushort4 o;
        o.x = Tt[(cc * 4 + 0) * 40 + r + rr];
        o.y = Tt[(cc * 4 + 1) * 40 + r + rr];
        o.z = Tt[(cc * 4 + 2) * 40 + r + rr];
        o.w = Tt[(cc * 4 + 3) * 40 + r + rr];
        *(ushort4*)&mt4[((size_t)cg * N_NODES + n0 + r + rr) * 4] = o;
    }
}

// ---------------- noisew: noiseW[n][32] = sqrt(lambda)*noise[n] @ Wrec + brec ---------------
__global__ __launch_bounds__(256) void k_noisew(const float* __restrict__ noise,
                                                const float* __restrict__ Wrec,
                                                const float* __restrict__ brec,
                                                float* __restrict__ noiseW) {
    __shared__ float Wr[4096];        // [k][o] 128x32 (16 KB)
    __shared__ float Ns[64 * 132];    // scaled noise rows (33.8 KB)
    __shared__ float brs[32];
    int tid = threadIdx.x;
    int n0 = blockIdx.x * 64;
    const float SQ = 0.03162277660168379f;
    for (int i = tid; i < 1024; i += 256)
        ((float4*)Wr)[i] = ((const float4*)Wrec)[i];
    if (tid < 32) brs[tid] = brec[tid];
    for (int i = tid; i < 1024; i += 256) {
        int row = i >> 4, u8 = i & 15;
        int n = n0 + row;
        float4 f0, f1;
        if (n < N_NODES) {
            f0 = ((const float4*)(noise + (size_t)n * 128))[u8 * 2];
            f1 = ((const float4*)(noise + (size_t)n * 128))[u8 * 2 + 1];
        } else {
            f0 = make_float4(0.f, 0.f, 0.f, 0.f);
            f1 = f0;
        }
        *(float4*)&Ns[row * 132 + u8 * 8]     = make_float4(SQ * f0.x, SQ * f0.y, SQ * f0.z, SQ * f0.w);
        *(float4*)&Ns[row * 132 + u8 * 8 + 4] = make_float4(SQ * f1.x, SQ * f1.y, SQ * f1.z, SQ * f1.w);
    }
    __syncthreads();
    int r = tid >> 2, q = (tid & 3) * 8;
    float4 acc0 = {0, 0, 0, 0}, acc1 = {0, 0, 0, 0};
    for (int k = 0; k < 128; ++k) {
        float nv = Ns[r * 132 + k];
        float4 w0 = *(const float4*)&Wr[k * 32 + q];
        float4 w1 = *(const float4*)&Wr[k * 32 + q + 4];
        acc0.x += nv * w0.x; acc0.y += nv * w0.y; acc0.z += nv * w0.z; acc0.w += nv * w0.w;
        acc1.x += nv * w1.x; acc1.y += nv * w1.y; acc1.z += nv * w1.z; acc1.w += nv * w1.w;
    }
    int n = n0 + r;
    if (n < N_NODES) {
        acc0.x += brs[q];     acc0.y += brs[q + 1]; acc0.z += brs[q + 2]; acc0.w += brs[q + 3];
        acc1.x += brs[q + 4]; acc1.y += brs[q + 5]; acc1.z += brs[q + 6]; acc1.w += brs[q + 7];
        ((float4*)(noiseW + (size_t)n * 32 + q))[0] = acc0;
        ((float4*)(noiseW + (size_t)n * 32 + q + 4))[0] = acc1;
    }
}

// ---------------- nodez: 512 thr = 128 nodes x 4 concept-quarters (round-4 verified, 91.6us) -
// Empirical optimum of tried variants (LDS-weights 120us / this 91.6 / packed 228 / 8-split
// 187). Weights via wave-uniform scalar loads from separate __restrict__ arrays; mt4 gives one
// coalesced 8B load per (concept,thread). LDS = 52.2KB staged combine scratch. DO NOT repack
// weights or deepen the concept split - both proven regressions.
__global__ __launch_bounds__(512) void k_nodez(const unsigned short* __restrict__ mt4,
                                               const float* __restrict__ Wz1,
                                               const float* __restrict__ bz1,
                                               const float* __restrict__ Wz2,
                                               const float* __restrict__ bz2,
                                               const float* __restrict__ Wrec,
                                               const float* __restrict__ noiseW,
                                               float* __restrict__ out) {
    __shared__ float scr[3 * 128 * 34];            // 52.2 KB partial-combine scratch
    int tid = threadIdx.x;
    int lt  = tid & 127;                           // node slot
    int qq  = tid >> 7;                            // concept quarter 0..3
    int c0  = __builtin_amdgcn_readfirstlane(qq * 8);
    int n = blockIdx.x * 128 + lt;
    bool ok = n < N_NODES;
    int m = ok ? n : (N_NODES - 1);

    const float4* W1 = (const float4*)Wz1;   // [c*32 + d*8 + g4]
    const float4* B1 = (const float4*)bz1;   // [c*8 + g4]
    const float4* W2 = (const float4*)Wz2;   // [c*32 + g]
    const float4* B2 = (const float4*)bz2;   // [c]
    const float4* WR = (const float4*)Wrec;  // [(c*4+d)*8 + o4]

    float4 o0 = {0,0,0,0}, o1 = {0,0,0,0}, o2 = {0,0,0,0}, o3 = {0,0,0,0};
    float4 o4v = {0,0,0,0}, o5 = {0,0,0,0}, o6 = {0,0,0,0}, o7 = {0,0,0,0};

    ushort4 mz = *(const ushort4*)&mt4[((size_t)c0 * N_NODES + m) * 4];

    for (int cc = 0; cc < 8; ++cc) {
        int c = c0 + cc;
        int cn = (cc < 7) ? (c + 1) : c;
        ushort4 nmz = *(const ushort4*)&mt4[((size_t)cn * N_NODES + m) * 4];
        float a0 = us2f(mz.x), a1 = us2f(mz.y), a2 = us2f(mz.z), a3 = us2f(mz.w);

        float4 zb = B2[c];
        float4 z = zb;
        #pragma unroll
        for (int g4 = 0; g4 < 8; ++g4) {
            float4 w0 = W1[c * 32 + g4];
            float4 w1 = W1[c * 32 + 8 + g4];
            float4 w2 = W1[c * 32 + 16 + g4];
            float4 w3 = W1[c * 32 + 24 + g4];
            float4 bb = B1[c * 8 + g4];
            float4 v;
            v.x = bb.x + a0 * w0.x + a1 * w1.x + a2 * w2.x + a3 * w3.x;
            v.y = bb.y + a0 * w0.y + a1 * w1.y + a2 * w2.y + a3 * w3.y;
            v.z = bb.z + a0 * w0.z + a1 * w1.z + a2 * w2.z + a3 * w3.z;
            v.w = bb.w + a0 * w0.w + a1 * w1.w + a2 * w2.w + a3 * w3.w;
            v.x = elu_fast(v.x); v.y = elu_fast(v.y); v.z = elu_fast(v.z); v.w = elu_fast(v.w);
            float4 u0 = W2[c * 32 + g4 * 4 + 0];
            float4 u1 = W2[c * 32 + g4 * 4 + 1];
            float4 u2 = W2[c * 32 + g4 * 4 + 2];
            float4 u3 = W2[c * 32 + g4 * 4 + 3];
            z.x += v.x * u0.x + v.y * u1.x + v.z * u2.x + v.w * u3.x;
            z.y += v.x * u0.y + v.y * u1.y + v.z * u2.y + v.w * u3.y;
            z.z += v.x * u0.z + v.y * u1.z + v.z * u2.z + v.w * u3.z;
            z.w += v.x * u0.w + v.y * u1.w + v.z * u2.w + v.w * u3.w;
        }
        #pragma unroll
        for (int d = 0; d < 4; ++d) {
            float zv = (&z.x)[d];
            const float4* wr = &WR[(c * 4 + d) * 8];
            float4 r0 = wr[0], r1 = wr[1], r2 = wr[2], r3 = wr[3];
            float4 r4 = wr[4], r5 = wr[5], r6 = wr[6], r7 = wr[7];
            o0.x += zv * r0.x; o0.y += zv * r0.y; o0.z += zv * r0.z; o0.w += zv * r0.w;
            o1.x += zv * r1.x; o1.y += zv * r1.y; o1.z += zv * r1.z; o1.w += zv * r1.w;
            o2.x += zv * r2.x; o2.y += zv * r2.y; o2.z += zv * r2.z; o2.w += zv * r2.w;
            o3.x += zv * r3.x; o3.y += zv * r3.y; o3.z += zv * r3.z; o3.w += zv * r3.w;
            o4v.x += zv * r4.x; o4v.y += zv * r4.y; o4v.z += zv * r4.z; o4v.w += zv * r4.w;
            o5.x += zv * r5.x; o5.y += zv * r5.y; o5.z += zv * r5.z; o5.w += zv * r5.w;
            o6.x += zv * r6.x; o6.y += zv * r6.y; o6.z += zv * r6.z; o6.w += zv * r6.w;
            o7.x += zv * r7.x; o7.y += zv * r7.y; o7.z += zv * r7.z; o7.w += zv * r7.w;
        }
        mz = nmz;
    }

    // ---- combine quarters through LDS ----
    __syncthreads();
    if (qq != 0) {
        float* p = &scr[((qq - 1) * 128 + lt) * 34];
        *(float2*)&p[0]  = make_float2(o0.x, o0.y);  *(float2*)&p[2]  = make_float2(o0.z, o0.w);
        *(float2*)&p[4]  = make_float2(o1.x, o1.y);  *(float2*)&p[6]  = make_float2(o1.z, o1.w);
        *(float2*)&p[8]  = make_float2(o2.x, o2.y);  *(float2*)&p[10] = make_float2(o2.z, o2.w);
        *(float2*)&p[12] = make_float2(o3.x, o3.y);  *(float2*)&p[14] = make_float2(o3.z, o3.w);
        *(float2*)&p[16] = make_float2(o4v.x, o4v.y); *(float2*)&p[18] = make_float2(o4v.z, o4v.w);
        *(float2*)&p[20] = make_float2(o5.x, o5.y);  *(float2*)&p[22] = make_float2(o5.z, o5.w);
        *(float2*)&p[24] = make_float2(o6.x, o6.y);  *(float2*)&p[26] = make_float2(o6.z, o6.w);
        *(float2*)&p[28] = make_float2(o7.x, o7.y);  *(float2*)&p[30] = make_float2(o7.z, o7.w);
    }
    __syncthreads();
    if (qq == 0 && ok) {
        const float* pA = &scr[lt * 34];
        const float* pB = &scr[(128 + lt) * 34];
        const float* pC = &scr[(256 + lt) * 34];
        const float4* nw = (const float4*)(noiseW + (size_t)n * 32);
        float4* po = (float4*)(out + (size_t)n * 32);
        float4 w, t;
        w = nw[0];
        t.x = o0.x + pA[0] + pB[0] + pC[0] + w.x;   t.y = o0.y + pA[1] + pB[1] + pC[1] + w.y;
        t.z = o0.z + pA[2] + pB[2] + pC[2] + w.z;   t.w = o0.w + pA[3] + pB[3] + pC[3] + w.w;
        po[0] = t;
        w = nw[1];
        t.x = o1.x + pA[4] + pB[4] + pC[4] + w.x;   t.y = o1.y + pA[5] + pB[5] + pC[5] + w.y;
        t.z = o1.z + pA[6] + pB[6] + pC[6] + w.z;   t.w = o1.w + pA[7] + pB[7] + pC[7] + w.w;
        po[1] = t;
        w = nw[2];
        t.x = o2.x + pA[8] + pB[8] + pC[8] + w.x;   t.y = o2.y + pA[9] + pB[9] + pC[9] + w.y;
        t.z = o2.z + pA[10] + pB[10] + pC[10] + w.z; t.w = o2.w + pA[11] + pB[11] + pC[11] + w.w;
        po[2] = t;
        w = nw[3];
        t.x = o3.x + pA[12] + pB[12] + pC[12] + w.x; t.y = o3.y + pA[13] + pB[13] + pC[13] + w.y;
        t.z = o3.z + pA[14] + pB[14] + pC[14] + w.z; t.w = o3.w + pA[15] + pB[15] + pC[15] + w.w;
        po[3] = t;
        w = nw[4];
        t.x = o4v.x + pA[16] + pB[16] + pC[16] + w.x; t.y = o4v.y + pA[17] + pB[17] + pC[17] + w.y;
        t.z = o4v.z + pA[18] + pB[18] + pC[18] + w.z; t.w = o4v.w + pA[19] + pB[19] + pC[19] + w.w;
        po[4] = t;
        w = nw[5];
        t.x = o5.x + pA[20] + pB[20] + pC[20] + w.x; t.y = o5.y + pA[21] + pB[21] + pC[21] + w.y;
        t.z = o5.z + pA[22] + pB[22] + pC[22] + w.z; t.w = o5.w + pA[23] + pB[23] + pC[23] + w.w;
        po[5] = t;
        w = nw[6];
        t.x = o6.x + pA[24] + pB[24] + pC[24] + w.x; t.y = o6.y + pA[25] + pB[25] + pC[25] + w.y;
        t.z = o6.z + pA[26] + pB[26] + pC[26] + w.z; t.w = o6.w + pA[27] + pB[27] + pC[27] + w.w;
        po[6] = t;
        w = nw[7];
        t.x = o7.x + pA[28] + pB[28] + pC[28] + w.x; t.y = o7.y + pA[29] + pB[29] + pC[29] + w.y;
        t.z = o7.z + pA[30] + pB[30] + pC[30] + w.z; t.w = o7.w + pA[31] + pB[31] + pC[31] + w.w;
        po[7] = t;
    }
}

// ---------------- label head: pred = MLP_c(A^T@label), one lane per node ---------------------
__global__ __launch_bounds__(256) void k_label(const float* __restrict__ label,
                                               const float* __restrict__ A,
                                               const float* __restrict__ Wl1,
                                               const float* __restrict__ bl1,
                                               const float* __restrict__ Wl2,
                                               const float* __restrict__ bl2,
                                               float* __restrict__ out) {
    __shared__ float As[1024], Wl1s[1024], bl1s[1024], Wl2s[1024], bl2s[32];
    int tid = threadIdx.x;
    for (int i = tid; i < 1024; i += 256) {
        As[i] = A[i];
        Wl1s[i] = Wl1[i];
        bl1s[i] = bl1[i];
        Wl2s[i] = Wl2[i];
    }
    if (tid < 32) bl2s[tid] = bl2[tid];
    __syncthreads();

    int n = blockIdx.x * 256 + tid;
    bool ok = n < N_NODES;
    int nn = ok ? n : (N_NODES - 1);

    float lab[32];
    #pragma unroll
    for (int q = 0; q < 8; ++q) {
        float4 lv = ((const float4*)(label + (size_t)nn * 32))[q];
        lab[q * 4 + 0] = lv.x; lab[q * 4 + 1] = lv.y;
        lab[q * 4 + 2] = lv.z; lab[q * 4 + 3] = lv.w;
    }
    float pred[32];
    for (int c = 0; c < 32; ++c) {
        float ml = 0.f;
        #pragma unroll
        for (int k = 0; k < 32; ++k) ml += As[k * 32 + c] * lab[k];
        float p = bl2s[c];
        #pragma unroll
        for (int g = 0; g < 32; ++g) {
            float h = elu_fast(ml * Wl1s[c * 32 + g] + bl1s[c * 32 + g]);
            p += h * Wl2s[c * 32 + g];
        }
        pred[c] = p;
    }
    if (ok) {
        #pragma unroll
        for (int q = 0; q < 8; ++q) {
            float4 v = {pred[q * 4 + 0], pred[q * 4 + 1], pred[q * 4 + 2], pred[q * 4 + 3]};
            ((float4*)(out + (size_t)N_NODES * 32 + (size_t)n * 32))[q] = v;
        }
    }
}

extern "C" void kernel_launch(void* const* d_in, const int* in_sizes, int n_in,
                              void* d_out, int out_size, void* d_ws, size_t ws_size,
                              hipStream_t stream) {
    const float* X      = (const float*)d_in[0];
    const float* label  = (const float*)d_in[1];
    const float* evalv  = (const float*)d_in[2];
    const float* noise  = (const float*)d_in[3];
    const float* W_base = (const float*)d_in[4];
    const float* W_mean = (const float*)d_in[5];
    // d_in[6] = W_logstd : dead code in the reference
    const float* A      = (const float*)d_in[7];
    const float* Wz1    = (const float*)d_in[8];
    const float* bz1    = (const float*)d_in[9];
    const float* Wz2    = (const float*)d_in[10];
    const float* bz2    = (const float*)d_in[11];
    const float* Wl1    = (const float*)d_in[12];
    const float* bl1    = (const float*)d_in[13];
    const float* Wl2    = (const float*)d_in[14];
    const float* bl2    = (const float*)d_in[15];
    const float* Wrec   = (const float*)d_in[16];
    const float* brec   = (const float*)d_in[17];
    const int* esrc = (const int*)d_in[18];
    const int* edst = (const int*)d_in[19];
    float* out = (float*)d_out;

    char* ws = (char*)d_ws;
    // Layout (~65.3 MB total; <= proven-safe 73.3 MB):
    float*          Wcomb        = (float*)(ws);                       // 64 KB
    float*          MmT          = (float*)(ws + 65536);               // 4 KB
    unsigned int*   bucket_deg   = (unsigned int*)(ws + 69632);        // 391 u32 (memset 2KB)
    unsigned int*   bucket_start = (unsigned int*)(ws + 71680);        // 392 u32
    unsigned int*   bucket_cursor= (unsigned int*)(ws + 73728);        // 391 u32
    unsigned int*   row_start    = (unsigned int*)(ws + 472064);       // N+1 u32
    uint2*          edge_sorted  = (uint2*)(ws + 1273984);             // 12.8 MB
    // slot A (25.6 MB): {coarse+coarse_dl scratch during bucket sort} -> hidden (bf16) -> mt4
    uint2*          coarse       = (uint2*)(ws + 14073984);            // 12.8 MB (dead before fuse1)
    unsigned char*  coarse_dl    = (unsigned char*)(ws + 26873984);    // 1.6 MB  (dead before fuse1)
    unsigned short* hidden       = (unsigned short*)(ws + 14073984);
    unsigned short* mt4          = (unsigned short*)(ws + 14073984);
    // slot B (25.6 MB): S2 (bf16) -> noiseW (f32, written after gemm2 consumes S2)
    unsigned short* S2           = (unsigned short*)(ws + 39673984);
    float*          noiseW       = (float*)(ws + 39673984);

    hipMemsetAsync(bucket_deg, 0, 2048, stream);
    k_inv<<<1, 64, 0, stream>>>(A, MmT);
    k_fold<<<16, 256, 0, stream>>>(MmT, W_mean, Wcomb);
    k_bhist<<<EHIST_G, 256, 0, stream>>>(edst, bucket_deg);
    k_bscan<<<1, 512, 0, stream>>>(bucket_deg, bucket_start, bucket_cursor);
    k_bucket1<<<EHIST_G, 256, 0, stream>>>(esrc, edst, evalv,
                                           bucket_cursor, coarse, coarse_dl);
    k_bucket2<<<NBUCK, 256, 0, stream>>>(bucket_start, coarse, coarse_dl,
                                         row_start, edge_sorted);
    k_fuse1<<<N_NODES / 8, 256, 0, stream>>>(row_start, edge_sorted, X, W_base, hidden);
    k_gather2<<<N_NODES / 8, 256, 0, stream>>>(row_start, edge_sorted, hidden, S2);
    k_gemm2<<<(N_NODES / 32) * 2, 256, 0, stream>>>(S2, Wcomb, mt4);
    k_noisew<<<(N_NODES + 63) / 64, 256, 0, stream>>>(noise, Wrec, brec, noiseW);
    k_nodez<<<(N_NODES + 127) / 128, 512, 0, stream>>>(mt4,
                                                       Wz1, bz1, Wz2, bz2,
                                                       Wrec, noiseW, out);
    k_label<<<(N_NODES + 255) / 256, 256, 0, stream>>>(label, A, Wl1, bl1, Wl2, bl2, out);
}

// Round 10
// 624.430 us; speedup vs baseline: 1.3448x; 1.0879x over previous
//
#include <hip/hip_runtime.h>
#include <hip/hip_bf16.h>

#define N_NODES 100000
#define N_EDGES 1600000
#define NBUCK   391          // ceil(100000/256) node-buckets of 256
#define EHIST_G 196          // ceil(1600000/8192) 8192-edge tiles

static __device__ __forceinline__ float us2f(unsigned short u) {
    union { unsigned int i; float f; } cv; cv.i = ((unsigned int)u) << 16; return cv.f;
}
static __device__ __forceinline__ unsigned short f2us(float f) {
    __hip_bfloat16 b = __float2bfloat16(f);
    union { __hip_bfloat16 b; unsigned short u; } cv; cv.b = b; return cv.u;
}
static __device__ __forceinline__ float elu_fast(float v) {
    return v > 0.f ? v : (__expf(v) - 1.0f);
}

// ---------------- prep: Gauss-Jordan inv (in-LDS) + fold, one 1024-thread block --------------
// MmT[j*32+c] = (A^T (I-A^T)^{-1})[c][j] stays in LDS; Wcomb[h][c*4+d] = sum_j Mm[c][j]*Wm[..].
__global__ __launch_bounds__(1024) void k_prep(const float* __restrict__ A,
                                               const float* __restrict__ Wm,
                                               float* __restrict__ Wcomb) {
    __shared__ float Af[1024];
    __shared__ float aug[32 * 65];
    __shared__ float MmTs[1024];
    __shared__ float fac[32];
    __shared__ float pv_s;
    int t = threadIdx.x;
    Af[t] = A[t];
    __syncthreads();
    for (int i = t; i < 2048; i += 1024) {
        int r = i >> 6, c = i & 63;
        float v;
        if (c < 32) v = (r == c ? 1.0f : 0.0f) - Af[c * 32 + r];
        else        v = ((c - 32) == r ? 1.0f : 0.0f);
        aug[r * 65 + c] = v;
    }
    __syncthreads();
    for (int k = 0; k < 32; ++k) {
        if (t == 0) pv_s = 1.0f / aug[k * 65 + k];
        __syncthreads();
        if (t < 64) aug[k * 65 + t] *= pv_s;
        __syncthreads();
        if (t < 32) fac[t] = aug[t * 65 + k];
        __syncthreads();
        for (int i = t; i < 2048; i += 1024) {
            int r = i >> 6, c = i & 63;
            if (r != k) aug[r * 65 + c] -= fac[r] * aug[k * 65 + c];
        }
        __syncthreads();
    }
    {
        int j = t >> 5, c = t & 31;
        float s = 0.f;
        #pragma unroll
        for (int k = 0; k < 32; ++k) s += Af[k * 32 + c] * aug[k * 65 + 32 + j];
        MmTs[t] = s;
    }
    __syncthreads();
    // fold: 4096 float4 outputs, 4 per thread
    for (int o = t; o < 4096; o += 1024) {
        int h = o >> 5, c = o & 31;
        float4 s = {0.f, 0.f, 0.f, 0.f};
        #pragma unroll
        for (int j = 0; j < 32; ++j) {
            float m = MmTs[j * 32 + c];
            float4 w = ((const float4*)Wm)[h * 32 + j];
            s.x += m * w.x; s.y += m * w.y; s.z += m * w.z; s.w += m * w.w;
        }
        ((float4*)Wcomb)[o] = s;
    }
}

// ---------------- x16: bf16 copy of X (halves fuse1's random-gather line count) --------------
__global__ __launch_bounds__(256) void k_x16(const float* __restrict__ X,
                                             unsigned short* __restrict__ Xh) {
    int i = blockIdx.x * 256 + threadIdx.x;     // 800000 float4s exactly
    float4 v = ((const float4*)X)[i];
    ushort4 o;
    o.x = f2us(v.x); o.y = f2us(v.y); o.z = f2us(v.z); o.w = f2us(v.w);
    ((ushort4*)Xh)[i] = o;
}

// ---------------- bhist: per-block bucket histograms -> blk_hist (reused by bucket1) ---------
__global__ __launch_bounds__(256) void k_bhist(const int* __restrict__ edst,
                                               unsigned int* __restrict__ blk_hist) {
    __shared__ unsigned int h[NBUCK];
    int tid = threadIdx.x;
    int e0 = blockIdx.x * 8192;
    for (int i = tid; i < NBUCK; i += 256) h[i] = 0u;
    __syncthreads();
    #pragma unroll 4
    for (int k = 0; k < 32; ++k) {
        int e = e0 + k * 256 + tid;
        if (e < N_EDGES) atomicAdd(&h[((unsigned)edst[e]) >> 8], 1u);
    }
    __syncthreads();
    for (int b = tid; b < NBUCK; b += 256)
        blk_hist[(size_t)blockIdx.x * NBUCK + b] = h[b];
}

// ---------------- bscan: column-sum blk_hist -> scan -> bucket_start/cursor ------------------
__global__ __launch_bounds__(512) void k_bscan(const unsigned int* __restrict__ blk_hist,
                                               unsigned int* __restrict__ bucket_start,
                                               unsigned int* __restrict__ bucket_cursor) {
    __shared__ unsigned int s[512];
    int tid = threadIdx.x;
    unsigned int v = 0u;
    if (tid < NBUCK) {
        for (int g = 0; g < EHIST_G; ++g)
            v += blk_hist[(size_t)g * NBUCK + tid];
    }
    s[tid] = v;
    __syncthreads();
    for (int off = 1; off < 512; off <<= 1) {
        unsigned int x = (tid >= off) ? s[tid - off] : 0u;
        __syncthreads();
        s[tid] += x;
        __syncthreads();
    }
    if (tid < NBUCK) {
        unsigned int excl = s[tid] - v;
        bucket_start[tid] = excl;
        bucket_cursor[tid] = excl;
    }
    if (tid == 0) bucket_start[NBUCK] = N_EDGES;
}

// ---------------- bucket1: coarse scatter, single edge pass (hist comes from blk_hist) -------
__global__ __launch_bounds__(256) void k_bucket1(const int* __restrict__ esrc,
                                                 const int* __restrict__ edst,
                                                 const float* __restrict__ evalv,
                                                 const unsigned int* __restrict__ blk_hist,
                                                 unsigned int* __restrict__ bucket_cursor,
                                                 uint2* __restrict__ coarse,
                                                 unsigned char* __restrict__ coarse_dl) {
    __shared__ unsigned int gbase[NBUCK];
    __shared__ unsigned int lcnt[NBUCK];
    int tid = threadIdx.x;
    int e0 = blockIdx.x * 8192;
    for (int b = tid; b < NBUCK; b += 256) {
        unsigned int h = blk_hist[(size_t)blockIdx.x * NBUCK + b];
        gbase[b] = h ? atomicAdd(&bucket_cursor[b], h) : 0u;
        lcnt[b] = 0u;
    }
    __syncthreads();
    #pragma unroll 4
    for (int k = 0; k < 32; ++k) {
        int e = e0 + k * 256 + tid;
        if (e < N_EDGES) {
            unsigned int d = (unsigned)edst[e];
            unsigned int b = d >> 8;
            unsigned int r = atomicAdd(&lcnt[b], 1u);
            unsigned int p = gbase[b] + r;
            uint2 ev;
            ev.x = (unsigned int)esrc[e];
            ev.y = __float_as_uint(evalv[e]);
            coarse[p] = ev;
            coarse_dl[p] = (unsigned char)(d & 255u);
        }
    }
}

// ---------------- bucket2: per-bucket LDS hist + scan -> row_start + fine sort (no gl atomics)
__global__ __launch_bounds__(256) void k_bucket2(const unsigned int* __restrict__ bucket_start,
                                                 const uint2* __restrict__ coarse,
                                                 const unsigned char* __restrict__ coarse_dl,
                                                 unsigned int* __restrict__ row_start,
                                                 uint2* __restrict__ edge_sorted) {
    __shared__ unsigned int h[256];
    __shared__ unsigned int sc[256];
    int b = blockIdx.x;
    int tid = threadIdx.x;
    unsigned int bs = bucket_start[b];
    unsigned int be = bucket_start[b + 1];
    h[tid] = 0u;
    __syncthreads();
    for (unsigned int i = bs + tid; i < be; i += 256)
        atomicAdd(&h[coarse_dl[i]], 1u);
    __syncthreads();
    unsigned int v = h[tid];
    sc[tid] = v;
    __syncthreads();
    for (int off = 1; off < 256; off <<= 1) {
        unsigned int x = (tid >= off) ? sc[tid - off] : 0u;
        __syncthreads();
        sc[tid] += x;
        __syncthreads();
    }
    unsigned int excl = sc[tid] - v;
    int node = (b << 8) + tid;
    if (node < N_NODES) row_start[node] = bs + excl;
    if (b == 0 && tid == 0) row_start[N_NODES] = N_EDGES;
    h[tid] = excl;                 // reuse as intra-bucket cursor
    __syncthreads();
    for (unsigned int i = bs + tid; i < be; i += 256) {
        uint2 ev = coarse[i];
        unsigned int dl = coarse_dl[i];
        unsigned int r = atomicAdd(&h[dl], 1u);
        edge_sorted[bs + r] = ev;
    }
}

// ---------------- fuse1: gather1 (bf16 X, 64B/row) + gemm1 fused. 8 nodes/block. -------------
__global__ __launch_bounds__(256) void k_fuse1(const unsigned int* __restrict__ row_start,
                                               const uint2* __restrict__ edge_sorted,
                                               const unsigned short* __restrict__ Xh,
                                               const float* __restrict__ Wb,
                                               unsigned short* __restrict__ hidden) {
    __shared__ float Wb_s[4096];      // 16 KB
    __shared__ float s1r[8 * 33];     // gathered rows, stride-33
    int tid = threadIdx.x;
    for (int i = tid; i < 1024; i += 256)
        ((float4*)Wb_s)[i] = ((const float4*)Wb)[i];

    int lane = tid & 31;
    int nd = tid >> 5;
    int n = blockIdx.x * 8 + nd;
    unsigned int i = row_start[n], e = row_start[n + 1];
    float a0 = 0.f, a1 = 0.f, a2 = 0.f, a3 = 0.f;
    for (; i + 4 <= e; i += 4) {
        uint2 ea = edge_sorted[i + 0], eb = edge_sorted[i + 1];
        uint2 ec = edge_sorted[i + 2], ed = edge_sorted[i + 3];
        float xa = us2f(Xh[(size_t)ea.x * 32 + lane]);
        float xb = us2f(Xh[(size_t)eb.x * 32 + lane]);
        float xc = us2f(Xh[(size_t)ec.x * 32 + lane]);
        float xd = us2f(Xh[(size_t)ed.x * 32 + lane]);
        a0 += __uint_as_float(ea.y) * xa;
        a1 += __uint_as_float(eb.y) * xb;
        a2 += __uint_as_float(ec.y) * xc;
        a3 += __uint_as_float(ed.y) * xd;
    }
    for (; i < e; ++i) {
        uint2 ea = edge_sorted[i];
        a0 += __uint_as_float(ea.y) * us2f(Xh[(size_t)ea.x * 32 + lane]);
    }
    s1r[nd * 33 + lane] = (a0 + a1) + (a2 + a3);
    __syncthreads();

    int q = lane * 4;
    float4 acc = {0.f, 0.f, 0.f, 0.f};
    #pragma unroll
    for (int k = 0; k < 32; ++k) {
        float v = s1r[nd * 33 + k];
        float4 w = *(const float4*)&Wb_s[k * 128 + q];
        acc.x += v * w.x; acc.y += v * w.y; acc.z += v * w.z; acc.w += v * w.w;
    }
    ushort4 o;
    o.x = f2us(fmaxf(acc.x, 0.f)); o.y = f2us(fmaxf(acc.y, 0.f));
    o.z = f2us(fmaxf(acc.z, 0.f)); o.w = f2us(fmaxf(acc.w, 0.f));
    *(ushort4*)&hidden[(size_t)n * 128 + q] = o;
}

// ---------------- gather2: S2[n][0:128] (bf16) = sum_e val*hidden[src]  (no LDS, unroll x4) ---
__global__ __launch_bounds__(256) void k_gather2(const unsigned int* __restrict__ row_start,
                                                 const uint2* __restrict__ edge_sorted,
                                                 const unsigned short* __restrict__ hidden,
                                                 unsigned short* __restrict__ S2) {
    int lane = threadIdx.x & 31;
    int n = blockIdx.x * 8 + (threadIdx.x >> 5);
    unsigned int i = row_start[n], e = row_start[n + 1];
    float4 A0 = {0, 0, 0, 0}, A1 = {0, 0, 0, 0}, A2 = {0, 0, 0, 0}, A3 = {0, 0, 0, 0};
    for (; i + 4 <= e; i += 4) {
        uint2 ea = edge_sorted[i + 0], eb = edge_sorted[i + 1];
        uint2 ec = edge_sorted[i + 2], ed = edge_sorted[i + 3];
        ushort4 ha = *(const ushort4*)&hidden[(size_t)ea.x * 128 + lane * 4];
        ushort4 hb = *(const ushort4*)&hidden[(size_t)eb.x * 128 + lane * 4];
        ushort4 hc = *(const ushort4*)&hidden[(size_t)ec.x * 128 + lane * 4];
        ushort4 hd = *(const ushort4*)&hidden[(size_t)ed.x * 128 + lane * 4];
        float va = __uint_as_float(ea.y), vb = __uint_as_float(eb.y);
        float vc = __uint_as_float(ec.y), vd = __uint_as_float(ed.y);
        A0.x += va * us2f(ha.x); A0.y += va * us2f(ha.y); A0.z += va * us2f(ha.z); A0.w += va * us2f(ha.w);
        A1.x += vb * us2f(hb.x); A1.y += vb * us2f(hb.y); A1.z += vb * us2f(hb.z); A1.w += vb * us2f(hb.w);
        A2.x += vc * us2f(hc.x); A2.y += vc * us2f(hc.y); A2.z += vc * us2f(hc.z); A2.w += vc * us2f(hc.w);
        A3.x += vd * us2f(hd.x); A3.y += vd * us2f(hd.y); A3.z += vd * us2f(hd.z); A3.w += vd * us2f(hd.w);
    }
    for (; i < e; ++i) {
        uint2 ea = edge_sorted[i];
        float v = __uint_as_float(ea.y);
        ushort4 h = *(const ushort4*)&hidden[(size_t)ea.x * 128 + lane * 4];
        A0.x += v * us2f(h.x); A0.y += v * us2f(h.y); A0.z += v * us2f(h.z); A0.w += v * us2f(h.w);
    }
    float4 acc;
    acc.x = (A0.x + A1.x) + (A2.x + A3.x);
    acc.y = (A0.y + A1.y) + (A2.y + A3.y);
    acc.z = (A0.z + A1.z) + (A2.z + A3.z);
    acc.w = (A0.w + A1.w) + (A2.w + A3.w);
    ushort4 o;
    o.x = f2us(acc.x); o.y = f2us(acc.y); o.z = f2us(acc.z); o.w = f2us(acc.w);
    *(ushort4*)&S2[(size_t)n * 128 + lane * 4] = o;
}

// ---------------- gemm2: mt4[c][n][d] (ushort4 per (c,n)) = (S2 @ Wcomb), [32n x 64j]/block --
__global__ __launch_bounds__(256) void k_gemm2(const unsigned short* __restrict__ S2,
                                               const float* __restrict__ Wc,
                                               unsigned short* __restrict__ mt4) {
    __shared__ float Wc_s[128 * 64];
    __shared__ float S2s[32 * 132];
    __shared__ unsigned short Tt[64 * 40];
    int tid = threadIdx.x;
    int rb = blockIdx.x >> 1;
    int j0 = (blockIdx.x & 1) * 64;
    int n0 = rb * 32;
    for (int idx = tid; idx < 2048; idx += 256) {
        int k = idx >> 4, jq = idx & 15;
        *(float4*)&Wc_s[k * 64 + jq * 4] = *(const float4*)&Wc[k * 128 + j0 + jq * 4];
    }
    for (int idx = tid; idx < 1024; idx += 256) {
        int r = idx >> 5, kq = idx & 31;
        ushort4 h = *(const ushort4*)&S2[(size_t)(n0 + r) * 128 + kq * 4];
        float4 f = {us2f(h.x), us2f(h.y), us2f(h.z), us2f(h.w)};
        *(float4*)&S2s[r * 132 + kq * 4] = f;
    }
    __syncthreads();
    int q = (tid & 15) * 4;
    int r0 = tid >> 4;
    float4 a0 = {0, 0, 0, 0}, a1 = {0, 0, 0, 0};
    for (int k4 = 0; k4 < 128; k4 += 4) {
        float4 s0 = *(const float4*)&S2s[r0 * 132 + k4];
        float4 s1 = *(const float4*)&S2s[(r0 + 16) * 132 + k4];
        #pragma unroll
        for (int kk = 0; kk < 4; ++kk) {
            float v0 = (&s0.x)[kk];
            float v1 = (&s1.x)[kk];
            float4 w = *(const float4*)&Wc_s[(k4 + kk) * 64 + q];
            a0.x += v0 * w.x; a0.y += v0 * w.y; a0.z += v0 * w.z; a0.w += v0 * w.w;
            a1.x += v1 * w.x; a1.y += v1 * w.y; a1.z += v1 * w.z; a1.w += v1 * w.w;
        }
    }
    #pragma unroll
    for (int c = 0; c < 4; ++c) {
        Tt[(q + c) * 40 + r0]      = f2us((&a0.x)[c]);
        Tt[(q + c) * 40 + r0 + 16] = f2us((&a1.x)[c]);
    }
    __syncthreads();
    int cc = tid >> 4;              // 0..15
    int r  = (tid & 15) * 2;        // node pair
    int cg = (j0 >> 2) + cc;        // global concept
    #pragma unroll
    for (int rr = 0; rr < 2; ++rr) {
        ushort4 o;
        o.x = Tt[(cc * 4 + 0) * 40 + r + rr];
        o.y = Tt[(cc * 4 + 1) * 40 + r + rr];
        o.z = Tt[(cc * 4 + 2) * 40 + r + rr];
        o.w = Tt[(cc * 4 + 3) * 40 + r + rr];
        *(ushort4*)&mt4[((size_t)cg * N_NODES + n0 + r + rr) * 4] = o;
    }
}

// ---------------- noisew: noiseW[n][32] = sqrt(lambda)*noise[n] @ Wrec + brec ---------------
__global__ __launch_bounds__(256) void k_noisew(const float* __restrict__ noise,
                                                const float* __restrict__ Wrec,
                                                const float* __restrict__ brec,
                                                float* __restrict__ noiseW) {
    __shared__ float Wr[4096];        // [k][o] 128x32 (16 KB)
    __shared__ float Ns[64 * 132];    // scaled noise rows (33.8 KB)
    __shared__ float brs[32];
    int tid = threadIdx.x;
    int n0 = blockIdx.x * 64;
    const float SQ = 0.03162277660168379f;
    for (int i = tid; i < 1024; i += 256)
        ((float4*)Wr)[i] = ((const float4*)Wrec)[i];
    if (tid < 32) brs[tid] = brec[tid];
    for (int i = tid; i < 1024; i += 256) {
        int row = i >> 4, u8 = i & 15;
        int n = n0 + row;
        float4 f0, f1;
        if (n < N_NODES) {
            f0 = ((const float4*)(noise + (size_t)n * 128))[u8 * 2];
            f1 = ((const float4*)(noise + (size_t)n * 128))[u8 * 2 + 1];
        } else {
            f0 = make_float4(0.f, 0.f, 0.f, 0.f);
            f1 = f0;
        }
        *(float4*)&Ns[row * 132 + u8 * 8]     = make_float4(SQ * f0.x, SQ * f0.y, SQ * f0.z, SQ * f0.w);
        *(float4*)&Ns[row * 132 + u8 * 8 + 4] = make_float4(SQ * f1.x, SQ * f1.y, SQ * f1.z, SQ * f1.w);
    }
    __syncthreads();
    int r = tid >> 2, q = (tid & 3) * 8;
    float4 acc0 = {0, 0, 0, 0}, acc1 = {0, 0, 0, 0};
    for (int k = 0; k < 128; ++k) {
        float nv = Ns[r * 132 + k];
        float4 w0 = *(const float4*)&Wr[k * 32 + q];
        float4 w1 = *(const float4*)&Wr[k * 32 + q + 4];
        acc0.x += nv * w0.x; acc0.y += nv * w0.y; acc0.z += nv * w0.z; acc0.w += nv * w0.w;
        acc1.x += nv * w1.x; acc1.y += nv * w1.y; acc1.z += nv * w1.z; acc1.w += nv * w1.w;
    }
    int n = n0 + r;
    if (n < N_NODES) {
        acc0.x += brs[q];     acc0.y += brs[q + 1]; acc0.z += brs[q + 2]; acc0.w += brs[q + 3];
        acc1.x += brs[q + 4]; acc1.y += brs[q + 5]; acc1.z += brs[q + 6]; acc1.w += brs[q + 7];
        ((float4*)(noiseW + (size_t)n * 32 + q))[0] = acc0;
        ((float4*)(noiseW + (size_t)n * 32 + q + 4))[0] = acc1;
    }
}

// ---------------- nodez: 512 thr = 128 nodes x 4 concept-quarters (round-4 verified, 91.6us) -
// Empirical optimum of tried variants (LDS-weights 120us / this 91.6 / packed 228 / 8-split
// 187). DO NOT repack weights or deepen the concept split - both proven regressions.
__global__ __launch_bounds__(512) void k_nodez(const unsigned short* __restrict__ mt4,
                                               const float* __restrict__ Wz1,
                                               const float* __restrict__ bz1,
                                               const float* __restrict__ Wz2,
                                               const float* __restrict__ bz2,
                                               const float* __restrict__ Wrec,
                                               const float* __restrict__ noiseW,
                                               float* __restrict__ out) {
    __shared__ float scr[3 * 128 * 34];            // 52.2 KB partial-combine scratch
    int tid = threadIdx.x;
    int lt  = tid & 127;                           // node slot
    int qq  = tid >> 7;                            // concept quarter 0..3
    int c0  = __builtin_amdgcn_readfirstlane(qq * 8);
    int n = blockIdx.x * 128 + lt;
    bool ok = n < N_NODES;
    int m = ok ? n : (N_NODES - 1);

    const float4* W1 = (const float4*)Wz1;   // [c*32 + d*8 + g4]
    const float4* B1 = (const float4*)bz1;   // [c*8 + g4]
    const float4* W2 = (const float4*)Wz2;   // [c*32 + g]
    const float4* B2 = (const float4*)bz2;   // [c]
    const float4* WR = (const float4*)Wrec;  // [(c*4+d)*8 + o4]

    float4 o0 = {0,0,0,0}, o1 = {0,0,0,0}, o2 = {0,0,0,0}, o3 = {0,0,0,0};
    float4 o4v = {0,0,0,0}, o5 = {0,0,0,0}, o6 = {0,0,0,0}, o7 = {0,0,0,0};

    ushort4 mz = *(const ushort4*)&mt4[((size_t)c0 * N_NODES + m) * 4];

    for (int cc = 0; cc < 8; ++cc) {
        int c = c0 + cc;
        int cn = (cc < 7) ? (c + 1) : c;
        ushort4 nmz = *(const ushort4*)&mt4[((size_t)cn * N_NODES + m) * 4];
        float a0 = us2f(mz.x), a1 = us2f(mz.y), a2 = us2f(mz.z), a3 = us2f(mz.w);

        float4 zb = B2[c];
        float4 z = zb;
        #pragma unroll
        for (int g4 = 0; g4 < 8; ++g4) {
            float4 w0 = W1[c * 32 + g4];
            float4 w1 = W1[c * 32 + 8 + g4];
            float4 w2 = W1[c * 32 + 16 + g4];
            float4 w3 = W1[c * 32 + 24 + g4];
            float4 bb = B1[c * 8 + g4];
            float4 v;
            v.x = bb.x + a0 * w0.x + a1 * w1.x + a2 * w2.x + a3 * w3.x;
            v.y = bb.y + a0 * w0.y + a1 * w1.y + a2 * w2.y + a3 * w3.y;
            v.z = bb.z + a0 * w0.z + a1 * w1.z + a2 * w2.z + a3 * w3.z;
            v.w = bb.w + a0 * w0.w + a1 * w1.w + a2 * w2.w + a3 * w3.w;
            v.x = elu_fast(v.x); v.y = elu_fast(v.y); v.z = elu_fast(v.z); v.w = elu_fast(v.w);
            float4 u0 = W2[c * 32 + g4 * 4 + 0];
            float4 u1 = W2[c * 32 + g4 * 4 + 1];
            float4 u2 = W2[c * 32 + g4 * 4 + 2];
            float4 u3 = W2[c * 32 + g4 * 4 + 3];
            z.x += v.x * u0.x + v.y * u1.x + v.z * u2.x + v.w * u3.x;
            z.y += v.x * u0.y + v.y * u1.y + v.z * u2.y + v.w * u3.y;
            z.z += v.x * u0.z + v.y * u1.z + v.z * u2.z + v.w * u3.z;
            z.w += v.x * u0.w + v.y * u1.w + v.z * u2.w + v.w * u3.w;
        }
        #pragma unroll
        for (int d = 0; d < 4; ++d) {
            float zv = (&z.x)[d];
            const float4* wr = &WR[(c * 4 + d) * 8];
            float4 r0 = wr[0], r1 = wr[1], r2 = wr[2], r3 = wr[3];
            float4 r4 = wr[4], r5 = wr[5], r6 = wr[6], r7 = wr[7];
            o0.x += zv * r0.x; o0.y += zv * r0.y; o0.z += zv * r0.z; o0.w += zv * r0.w;
            o1.x += zv * r1.x; o1.y += zv * r1.y; o1.z += zv * r1.z; o1.w += zv * r1.w;
            o2.x += zv * r2.x; o2.y += zv * r2.y; o2.z += zv * r2.z; o2.w += zv * r2.w;
            o3.x += zv * r3.x; o3.y += zv * r3.y; o3.z += zv * r3.z; o3.w += zv * r3.w;
            o4v.x += zv * r4.x; o4v.y += zv * r4.y; o4v.z += zv * r4.z; o4v.w += zv * r4.w;
            o5.x += zv * r5.x; o5.y += zv * r5.y; o5.z += zv * r5.z; o5.w += zv * r5.w;
            o6.x += zv * r6.x; o6.y += zv * r6.y; o6.z += zv * r6.z; o6.w += zv * r6.w;
            o7.x += zv * r7.x; o7.y += zv * r7.y; o7.z += zv * r7.z; o7.w += zv * r7.w;
        }
        mz = nmz;
    }

    // ---- combine quarters through LDS ----
    __syncthreads();
    if (qq != 0) {
        float* p = &scr[((qq - 1) * 128 + lt) * 34];
        *(float2*)&p[0]  = make_float2(o0.x, o0.y);  *(float2*)&p[2]  = make_float2(o0.z, o0.w);
        *(float2*)&p[4]  = make_float2(o1.x, o1.y);  *(float2*)&p[6]  = make_float2(o1.z, o1.w);
        *(float2*)&p[8]  = make_float2(o2.x, o2.y);  *(float2*)&p[10] = make_float2(o2.z, o2.w);
        *(float2*)&p[12] = make_float2(o3.x, o3.y);  *(float2*)&p[14] = make_float2(o3.z, o3.w);
        *(float2*)&p[16] = make_float2(o4v.x, o4v.y); *(float2*)&p[18] = make_float2(o4v.z, o4v.w);
        *(float2*)&p[20] = make_float2(o5.x, o5.y);  *(float2*)&p[22] = make_float2(o5.z, o5.w);
        *(float2*)&p[24] = make_float2(o6.x, o6.y);  *(float2*)&p[26] = make_float2(o6.z, o6.w);
        *(float2*)&p[28] = make_float2(o7.x, o7.y);  *(float2*)&p[30] = make_float2(o7.z, o7.w);
    }
    __syncthreads();
    if (qq == 0 && ok) {
        const float* pA = &scr[lt * 34];
        const float* pB = &scr[(128 + lt) * 34];
        const float* pC = &scr[(256 + lt) * 34];
        const float4* nw = (const float4*)(noiseW + (size_t)n * 32);
        float4* po = (float4*)(out + (size_t)n * 32);
        float4 w, t;
        w = nw[0];
        t.x = o0.x + pA[0] + pB[0] + pC[0] + w.x;   t.y = o0.y + pA[1] + pB[1] + pC[1] + w.y;
        t.z = o0.z + pA[2] + pB[2] + pC[2] + w.z;   t.w = o0.w + pA[3] + pB[3] + pC[3] + w.w;
        po[0] = t;
        w = nw[1];
        t.x = o1.x + pA[4] + pB[4] + pC[4] + w.x;   t.y = o1.y + pA[5] + pB[5] + pC[5] + w.y;
        t.z = o1.z + pA[6] + pB[6] + pC[6] + w.z;   t.w = o1.w + pA[7] + pB[7] + pC[7] + w.w;
        po[1] = t;
        w = nw[2];
        t.x = o2.x + pA[8] + pB[8] + pC[8] + w.x;   t.y = o2.y + pA[9] + pB[9] + pC[9] + w.y;
        t.z = o2.z + pA[10] + pB[10] + pC[10] + w.z; t.w = o2.w + pA[11] + pB[11] + pC[11] + w.w;
        po[2] = t;
        w = nw[3];
        t.x = o3.x + pA[12] + pB[12] + pC[12] + w.x; t.y = o3.y + pA[13] + pB[13] + pC[13] + w.y;
        t.z = o3.z + pA[14] + pB[14] + pC[14] + w.z; t.w = o3.w + pA[15] + pB[15] + pC[15] + w.w;
        po[3] = t;
        w = nw[4];
        t.x = o4v.x + pA[16] + pB[16] + pC[16] + w.x; t.y = o4v.y + pA[17] + pB[17] + pC[17] + w.y;
        t.z = o4v.z + pA[18] + pB[18] + pC[18] + w.z; t.w = o4v.w + pA[19] + pB[19] + pC[19] + w.w;
        po[4] = t;
        w = nw[5];
        t.x = o5.x + pA[20] + pB[20] + pC[20] + w.x; t.y = o5.y + pA[21] + pB[21] + pC[21] + w.y;
        t.z = o5.z + pA[22] + pB[22] + pC[22] + w.z; t.w = o5.w + pA[23] + pB[23] + pC[23] + w.w;
        po[5] = t;
        w = nw[6];
        t.x = o6.x + pA[24] + pB[24] + pC[24] + w.x; t.y = o6.y + pA[25] + pB[25] + pC[25] + w.y;
        t.z = o6.z + pA[26] + pB[26] + pC[26] + w.z; t.w = o6.w + pA[27] + pB[27] + pC[27] + w.w;
        po[6] = t;
        w = nw[7];
        t.x = o7.x + pA[28] + pB[28] + pC[28] + w.x; t.y = o7.y + pA[29] + pB[29] + pC[29] + w.y;
        t.z = o7.z + pA[30] + pB[30] + pC[30] + w.z; t.w = o7.w + pA[31] + pB[31] + pC[31] + w.w;
        po[7] = t;
    }
}

// ---------------- label head: pred = MLP_c(A^T@label), one lane per node ---------------------
__global__ __launch_bounds__(256) void k_label(const float* __restrict__ label,
                                               const float* __restrict__ A,
                                               const float* __restrict__ Wl1,
                                               const float* __restrict__ bl1,
                                               const float* __restrict__ Wl2,
                                               const float* __restrict__ bl2,
                                               float* __restrict__ out) {
    __shared__ float As[1024], Wl1s[1024], bl1s[1024], Wl2s[1024], bl2s[32];
    int tid = threadIdx.x;
    for (int i = tid; i < 1024; i += 256) {
        As[i] = A[i];
        Wl1s[i] = Wl1[i];
        bl1s[i] = bl1[i];
        Wl2s[i] = Wl2[i];
    }
    if (tid < 32) bl2s[tid] = bl2[tid];
    __syncthreads();

    int n = blockIdx.x * 256 + tid;
    bool ok = n < N_NODES;
    int nn = ok ? n : (N_NODES - 1);

    float lab[32];
    #pragma unroll
    for (int q = 0; q < 8; ++q) {
        float4 lv = ((const float4*)(label + (size_t)nn * 32))[q];
        lab[q * 4 + 0] = lv.x; lab[q * 4 + 1] = lv.y;
        lab[q * 4 + 2] = lv.z; lab[q * 4 + 3] = lv.w;
    }
    float pred[32];
    for (int c = 0; c < 32; ++c) {
        float ml = 0.f;
        #pragma unroll
        for (int k = 0; k < 32; ++k) ml += As[k * 32 + c] * lab[k];
        float p = bl2s[c];
        #pragma unroll
        for (int g = 0; g < 32; ++g) {
            float h = elu_fast(ml * Wl1s[c * 32 + g] + bl1s[c * 32 + g]);
            p += h * Wl2s[c * 32 + g];
        }
        pred[c] = p;
    }
    if (ok) {
        #pragma unroll
        for (int q = 0; q < 8; ++q) {
            float4 v = {pred[q * 4 + 0], pred[q * 4 + 1], pred[q * 4 + 2], pred[q * 4 + 3]};
            ((float4*)(out + (size_t)N_NODES * 32 + (size_t)n * 32))[q] = v;
        }
    }
}

extern "C" void kernel_launch(void* const* d_in, const int* in_sizes, int n_in,
                              void* d_out, int out_size, void* d_ws, size_t ws_size,
                              hipStream_t stream) {
    const float* X      = (const float*)d_in[0];
    const float* label  = (const float*)d_in[1];
    const float* evalv  = (const float*)d_in[2];
    const float* noise  = (const float*)d_in[3];
    const float* W_base = (const float*)d_in[4];
    const float* W_mean = (const float*)d_in[5];
    // d_in[6] = W_logstd : dead code in the reference
    const float* A      = (const float*)d_in[7];
    const float* Wz1    = (const float*)d_in[8];
    const float* bz1    = (const float*)d_in[9];
    const float* Wz2    = (const float*)d_in[10];
    const float* bz2    = (const float*)d_in[11];
    const float* Wl1    = (const float*)d_in[12];
    const float* bl1    = (const float*)d_in[13];
    const float* Wl2    = (const float*)d_in[14];
    const float* bl2    = (const float*)d_in[15];
    const float* Wrec   = (const float*)d_in[16];
    const float* brec   = (const float*)d_in[17];
    const int* esrc = (const int*)d_in[18];
    const int* edst = (const int*)d_in[19];
    float* out = (float*)d_out;

    char* ws = (char*)d_ws;
    // Layout (~71.7 MB total; <= proven-safe 73.3 MB):
    float*          Wcomb        = (float*)(ws);                       // 64 KB
    unsigned int*   bucket_start = (unsigned int*)(ws + 71680);        // 392 u32
    unsigned int*   bucket_cursor= (unsigned int*)(ws + 73728);        // 391 u32
    unsigned int*   blk_hist     = (unsigned int*)(ws + 76800);        // 196*391 u32 = 306.5 KB
    unsigned int*   row_start    = (unsigned int*)(ws + 472064);       // N+1 u32
    uint2*          edge_sorted  = (uint2*)(ws + 1273984);             // 12.8 MB
    // slot A (25.6 MB): {coarse+coarse_dl scratch during bucket sort} -> hidden (bf16) -> mt4
    uint2*          coarse       = (uint2*)(ws + 14073984);            // 12.8 MB (dead before fuse1)
    unsigned char*  coarse_dl    = (unsigned char*)(ws + 26873984);    // 1.6 MB  (dead before fuse1)
    unsigned short* hidden       = (unsigned short*)(ws + 14073984);
    unsigned short* mt4          = (unsigned short*)(ws + 14073984);
    // slot B (25.6 MB): S2 (bf16) -> noiseW (f32); ends at 65273984
    unsigned short* S2           = (unsigned short*)(ws + 39673984);
    float*          noiseW       = (float*)(ws + 39673984);
    // Xh (bf16 X copy) past slot B end (lesson from round-5 aliasing bug: never inside a slot)
    unsigned short* Xh           = (unsigned short*)(ws + 65273984);   // 6.4 MB -> ends 71.7 MB

    k_prep<<<1, 1024, 0, stream>>>(A, W_mean, Wcomb);
    k_x16<<<800000 / 256, 256, 0, stream>>>(X, Xh);
    k_bhist<<<EHIST_G, 256, 0, stream>>>(edst, blk_hist);
    k_bscan<<<1, 512, 0, stream>>>(blk_hist, bucket_start, bucket_cursor);
    k_bucket1<<<EHIST_G, 256, 0, stream>>>(esrc, edst, evalv, blk_hist,
                                           bucket_cursor, coarse, coarse_dl);
    k_bucket2<<<NBUCK, 256, 0, stream>>>(bucket_start, coarse, coarse_dl,
                                         row_start, edge_sorted);
    k_fuse1<<<N_NODES / 8, 256, 0, stream>>>(row_start, edge_sorted, Xh, W_base, hidden);
    k_gather2<<<N_NODES / 8, 256, 0, stream>>>(row_start, edge_sorted, hidden, S2);
    k_gemm2<<<(N_NODES / 32) * 2, 256, 0, stream>>>(S2, Wcomb, mt4);
    k_noisew<<<(N_NODES + 63) / 64, 256, 0, stream>>>(noise, Wrec, brec, noiseW);
    k_nodez<<<(N_NODES + 127) / 128, 512, 0, stream>>>(mt4,
                                                       Wz1, bz1, Wz2, bz2,
                                                       Wrec, noiseW, out);
    k_label<<<(N_NODES + 255) / 256, 256, 0, stream>>>(label, A, Wl1, bl1, Wl2, bl2, out);
}

// Round 11
// 602.118 us; speedup vs baseline: 1.3946x; 1.0371x over previous
//
#include <hip/hip_runtime.h>
#include <hip/hip_bf16.h>

#define N_NODES 100000
#define N_EDGES 1600000
#define NBUCK   391          // ceil(100000/256) node-buckets of 256
#define EHIST_G 196          // ceil(1600000/8192) 8192-edge tiles

static __device__ __forceinline__ float us2f(unsigned short u) {
    union { unsigned int i; float f; } cv; cv.i = ((unsigned int)u) << 16; return cv.f;
}
static __device__ __forceinline__ unsigned short f2us(float f) {
    __hip_bfloat16 b = __float2bfloat16(f);
    union { __hip_bfloat16 b; unsigned short u; } cv; cv.b = b; return cv.u;
}
static __device__ __forceinline__ float elu_fast(float v) {
    return v > 0.f ? v : (__expf(v) - 1.0f);
}

// ---------------- prep: Gauss-Jordan inv (in-LDS) + fold, one 1024-thread block --------------
__global__ __launch_bounds__(1024) void k_prep(const float* __restrict__ A,
                                               const float* __restrict__ Wm,
                                               float* __restrict__ Wcomb) {
    __shared__ float Af[1024];
    __shared__ float aug[32 * 65];
    __shared__ float MmTs[1024];
    __shared__ float fac[32];
    __shared__ float pv_s;
    int t = threadIdx.x;
    Af[t] = A[t];
    __syncthreads();
    for (int i = t; i < 2048; i += 1024) {
        int r = i >> 6, c = i & 63;
        float v;
        if (c < 32) v = (r == c ? 1.0f : 0.0f) - Af[c * 32 + r];
        else        v = ((c - 32) == r ? 1.0f : 0.0f);
        aug[r * 65 + c] = v;
    }
    __syncthreads();
    for (int k = 0; k < 32; ++k) {
        if (t == 0) pv_s = 1.0f / aug[k * 65 + k];
        __syncthreads();
        if (t < 64) aug[k * 65 + t] *= pv_s;
        __syncthreads();
        if (t < 32) fac[t] = aug[t * 65 + k];
        __syncthreads();
        for (int i = t; i < 2048; i += 1024) {
            int r = i >> 6, c = i & 63;
            if (r != k) aug[r * 65 + c] -= fac[r] * aug[k * 65 + c];
        }
        __syncthreads();
    }
    {
        int j = t >> 5, c = t & 31;
        float s = 0.f;
        #pragma unroll
        for (int k = 0; k < 32; ++k) s += Af[k * 32 + c] * aug[k * 65 + 32 + j];
        MmTs[t] = s;
    }
    __syncthreads();
    for (int o = t; o < 4096; o += 1024) {
        int h = o >> 5, c = o & 31;
        float4 s = {0.f, 0.f, 0.f, 0.f};
        #pragma unroll
        for (int j = 0; j < 32; ++j) {
            float m = MmTs[j * 32 + c];
            float4 w = ((const float4*)Wm)[h * 32 + j];
            s.x += m * w.x; s.y += m * w.y; s.z += m * w.z; s.w += m * w.w;
        }
        ((float4*)Wcomb)[o] = s;
    }
}

// ---------------- x16: bf16 copy of X (halves fuse1's random-gather line count) --------------
__global__ __launch_bounds__(256) void k_x16(const float* __restrict__ X,
                                             unsigned short* __restrict__ Xh) {
    int i = blockIdx.x * 256 + threadIdx.x;     // 800000 float4s exactly
    float4 v = ((const float4*)X)[i];
    ushort4 o;
    o.x = f2us(v.x); o.y = f2us(v.y); o.z = f2us(v.z); o.w = f2us(v.w);
    ((ushort4*)Xh)[i] = o;
}

// ---------------- bhist: per-block bucket histograms -> blk_hist (reused by bucket1) ---------
__global__ __launch_bounds__(256) void k_bhist(const int* __restrict__ edst,
                                               unsigned int* __restrict__ blk_hist) {
    __shared__ unsigned int h[NBUCK];
    int tid = threadIdx.x;
    int e0 = blockIdx.x * 8192;
    for (int i = tid; i < NBUCK; i += 256) h[i] = 0u;
    __syncthreads();
    #pragma unroll 4
    for (int k = 0; k < 32; ++k) {
        int e = e0 + k * 256 + tid;
        if (e < N_EDGES) atomicAdd(&h[((unsigned)edst[e]) >> 8], 1u);
    }
    __syncthreads();
    for (int b = tid; b < NBUCK; b += 256)
        blk_hist[(size_t)blockIdx.x * NBUCK + b] = h[b];
}

// ---------------- bscan: column-sum blk_hist -> scan -> bucket_start/cursor ------------------
__global__ __launch_bounds__(512) void k_bscan(const unsigned int* __restrict__ blk_hist,
                                               unsigned int* __restrict__ bucket_start,
                                               unsigned int* __restrict__ bucket_cursor) {
    __shared__ unsigned int s[512];
    int tid = threadIdx.x;
    unsigned int v = 0u;
    if (tid < NBUCK) {
        for (int g = 0; g < EHIST_G; ++g)
            v += blk_hist[(size_t)g * NBUCK + tid];
    }
    s[tid] = v;
    __syncthreads();
    for (int off = 1; off < 512; off <<= 1) {
        unsigned int x = (tid >= off) ? s[tid - off] : 0u;
        __syncthreads();
        s[tid] += x;
        __syncthreads();
    }
    if (tid < NBUCK) {
        unsigned int excl = s[tid] - v;
        bucket_start[tid] = excl;
        bucket_cursor[tid] = excl;
    }
    if (tid == 0) bucket_start[NBUCK] = N_EDGES;
}

// ---------------- bucket1: coarse scatter, single edge pass (hist comes from blk_hist) -------
__global__ __launch_bounds__(256) void k_bucket1(const int* __restrict__ esrc,
                                                 const int* __restrict__ edst,
                                                 const float* __restrict__ evalv,
                                                 const unsigned int* __restrict__ blk_hist,
                                                 unsigned int* __restrict__ bucket_cursor,
                                                 uint2* __restrict__ coarse,
                                                 unsigned char* __restrict__ coarse_dl) {
    __shared__ unsigned int gbase[NBUCK];
    __shared__ unsigned int lcnt[NBUCK];
    int tid = threadIdx.x;
    int e0 = blockIdx.x * 8192;
    for (int b = tid; b < NBUCK; b += 256) {
        unsigned int h = blk_hist[(size_t)blockIdx.x * NBUCK + b];
        gbase[b] = h ? atomicAdd(&bucket_cursor[b], h) : 0u;
        lcnt[b] = 0u;
    }
    __syncthreads();
    #pragma unroll 4
    for (int k = 0; k < 32; ++k) {
        int e = e0 + k * 256 + tid;
        if (e < N_EDGES) {
            unsigned int d = (unsigned)edst[e];
            unsigned int b = d >> 8;
            unsigned int r = atomicAdd(&lcnt[b], 1u);
            unsigned int p = gbase[b] + r;
            uint2 ev;
            ev.x = (unsigned int)esrc[e];
            ev.y = __float_as_uint(evalv[e]);
            coarse[p] = ev;
            coarse_dl[p] = (unsigned char)(d & 255u);
        }
    }
}

// ---------------- bucket2: per-bucket LDS hist + scan -> row_start + fine sort (no gl atomics)
__global__ __launch_bounds__(256) void k_bucket2(const unsigned int* __restrict__ bucket_start,
                                                 const uint2* __restrict__ coarse,
                                                 const unsigned char* __restrict__ coarse_dl,
                                                 unsigned int* __restrict__ row_start,
                                                 uint2* __restrict__ edge_sorted) {
    __shared__ unsigned int h[256];
    __shared__ unsigned int sc[256];
    int b = blockIdx.x;
    int tid = threadIdx.x;
    unsigned int bs = bucket_start[b];
    unsigned int be = bucket_start[b + 1];
    h[tid] = 0u;
    __syncthreads();
    for (unsigned int i = bs + tid; i < be; i += 256)
        atomicAdd(&h[coarse_dl[i]], 1u);
    __syncthreads();
    unsigned int v = h[tid];
    sc[tid] = v;
    __syncthreads();
    for (int off = 1; off < 256; off <<= 1) {
        unsigned int x = (tid >= off) ? sc[tid - off] : 0u;
        __syncthreads();
        sc[tid] += x;
        __syncthreads();
    }
    unsigned int excl = sc[tid] - v;
    int node = (b << 8) + tid;
    if (node < N_NODES) row_start[node] = bs + excl;
    if (b == 0 && tid == 0) row_start[N_NODES] = N_EDGES;
    h[tid] = excl;                 // reuse as intra-bucket cursor
    __syncthreads();
    for (unsigned int i = bs + tid; i < be; i += 256) {
        uint2 ev = coarse[i];
        unsigned int dl = coarse_dl[i];
        unsigned int r = atomicAdd(&h[dl], 1u);
        edge_sorted[bs + r] = ev;
    }
}

// ---------------- fuse1: gather1 (bf16 X, 64B/row) + gemm1 fused. 8 nodes/block. -------------
__global__ __launch_bounds__(256) void k_fuse1(const unsigned int* __restrict__ row_start,
                                               const uint2* __restrict__ edge_sorted,
                                               const unsigned short* __restrict__ Xh,
                                               const float* __restrict__ Wb,
                                               unsigned short* __restrict__ hidden) {
    __shared__ float Wb_s[4096];      // 16 KB
    __shared__ float s1r[8 * 33];     // gathered rows, stride-33
    int tid = threadIdx.x;
    for (int i = tid; i < 1024; i += 256)
        ((float4*)Wb_s)[i] = ((const float4*)Wb)[i];

    int lane = tid & 31;
    int nd = tid >> 5;
    int n = blockIdx.x * 8 + nd;
    unsigned int i = row_start[n], e = row_start[n + 1];
    float a0 = 0.f, a1 = 0.f, a2 = 0.f, a3 = 0.f;
    for (; i + 4 <= e; i += 4) {
        uint2 ea = edge_sorted[i + 0], eb = edge_sorted[i + 1];
        uint2 ec = edge_sorted[i + 2], ed = edge_sorted[i + 3];
        float xa = us2f(Xh[(size_t)ea.x * 32 + lane]);
        float xb = us2f(Xh[(size_t)eb.x * 32 + lane]);
        float xc = us2f(Xh[(size_t)ec.x * 32 + lane]);
        float xd = us2f(Xh[(size_t)ed.x * 32 + lane]);
        a0 += __uint_as_float(ea.y) * xa;
        a1 += __uint_as_float(eb.y) * xb;
        a2 += __uint_as_float(ec.y) * xc;
        a3 += __uint_as_float(ed.y) * xd;
    }
    for (; i < e; ++i) {
        uint2 ea = edge_sorted[i];
        a0 += __uint_as_float(ea.y) * us2f(Xh[(size_t)ea.x * 32 + lane]);
    }
    s1r[nd * 33 + lane] = (a0 + a1) + (a2 + a3);
    __syncthreads();

    int q = lane * 4;
    float4 acc = {0.f, 0.f, 0.f, 0.f};
    #pragma unroll
    for (int k = 0; k < 32; ++k) {
        float v = s1r[nd * 33 + k];
        float4 w = *(const float4*)&Wb_s[k * 128 + q];
        acc.x += v * w.x; acc.y += v * w.y; acc.z += v * w.z; acc.w += v * w.w;
    }
    ushort4 o;
    o.x = f2us(fmaxf(acc.x, 0.f)); o.y = f2us(fmaxf(acc.y, 0.f));
    o.z = f2us(fmaxf(acc.z, 0.f)); o.w = f2us(fmaxf(acc.w, 0.f));
    *(ushort4*)&hidden[(size_t)n * 128 + q] = o;
}

// ---------------- gather2: S2[n][0:128] (bf16) = sum_e val*hidden[src]  (no LDS, unroll x4) ---
__global__ __launch_bounds__(256) void k_gather2(const unsigned int* __restrict__ row_start,
                                                 const uint2* __restrict__ edge_sorted,
                                                 const unsigned short* __restrict__ hidden,
                                                 unsigned short* __restrict__ S2) {
    int lane = threadIdx.x & 31;
    int n = blockIdx.x * 8 + (threadIdx.x >> 5);
    unsigned int i = row_start[n], e = row_start[n + 1];
    float4 A0 = {0, 0, 0, 0}, A1 = {0, 0, 0, 0}, A2 = {0, 0, 0, 0}, A3 = {0, 0, 0, 0};
    for (; i + 4 <= e; i += 4) {
        uint2 ea = edge_sorted[i + 0], eb = edge_sorted[i + 1];
        uint2 ec = edge_sorted[i + 2], ed = edge_sorted[i + 3];
        ushort4 ha = *(const ushort4*)&hidden[(size_t)ea.x * 128 + lane * 4];
        ushort4 hb = *(const ushort4*)&hidden[(size_t)eb.x * 128 + lane * 4];
        ushort4 hc = *(const ushort4*)&hidden[(size_t)ec.x * 128 + lane * 4];
        ushort4 hd = *(const ushort4*)&hidden[(size_t)ed.x * 128 + lane * 4];
        float va = __uint_as_float(ea.y), vb = __uint_as_float(eb.y);
        float vc = __uint_as_float(ec.y), vd = __uint_as_float(ed.y);
        A0.x += va * us2f(ha.x); A0.y += va * us2f(ha.y); A0.z += va * us2f(ha.z); A0.w += va * us2f(ha.w);
        A1.x += vb * us2f(hb.x); A1.y += vb * us2f(hb.y); A1.z += vb * us2f(hb.z); A1.w += vb * us2f(hb.w);
        A2.x += vc * us2f(hc.x); A2.y += vc * us2f(hc.y); A2.z += vc * us2f(hc.z); A2.w += vc * us2f(hc.w);
        A3.x += vd * us2f(hd.x); A3.y += vd * us2f(hd.y); A3.z += vd * us2f(hd.z); A3.w += vd * us2f(hd.w);
    }
    for (; i < e; ++i) {
        uint2 ea = edge_sorted[i];
        float v = __uint_as_float(ea.y);
        ushort4 h = *(const ushort4*)&hidden[(size_t)ea.x * 128 + lane * 4];
        A0.x += v * us2f(h.x); A0.y += v * us2f(h.y); A0.z += v * us2f(h.z); A0.w += v * us2f(h.w);
    }
    float4 acc;
    acc.x = (A0.x + A1.x) + (A2.x + A3.x);
    acc.y = (A0.y + A1.y) + (A2.y + A3.y);
    acc.z = (A0.z + A1.z) + (A2.z + A3.z);
    acc.w = (A0.w + A1.w) + (A2.w + A3.w);
    ushort4 o;
    o.x = f2us(acc.x); o.y = f2us(acc.y); o.z = f2us(acc.z); o.w = f2us(acc.w);
    *(ushort4*)&S2[(size_t)n * 128 + lane * 4] = o;
}

// ---------------- gemm2: mt4[c][n][d] (ushort4 per (c,n)) = (S2 @ Wcomb), [32n x 64j]/block --
__global__ __launch_bounds__(256) void k_gemm2(const unsigned short* __restrict__ S2,
                                               const float* __restrict__ Wc,
                                               unsigned short* __restrict__ mt4) {
    __shared__ float Wc_s[128 * 64];
    __shared__ float S2s[32 * 132];
    __shared__ unsigned short Tt[64 * 40];
    int tid = threadIdx.x;
    int rb = blockIdx.x >> 1;
    int j0 = (blockIdx.x & 1) * 64;
    int n0 = rb * 32;
    for (int idx = tid; idx < 2048; idx += 256) {
        int k = idx >> 4, jq = idx & 15;
        *(float4*)&Wc_s[k * 64 + jq * 4] = *(const float4*)&Wc[k * 128 + j0 + jq * 4];
    }
    for (int idx = tid; idx < 1024; idx += 256) {
        int r = idx >> 5, kq = idx & 31;
        ushort4 h = *(const ushort4*)&S2[(size_t)(n0 + r) * 128 + kq * 4];
        float4 f = {us2f(h.x), us2f(h.y), us2f(h.z), us2f(h.w)};
        *(float4*)&S2s[r * 132 + kq * 4] = f;
    }
    __syncthreads();
    int q = (tid & 15) * 4;
    int r0 = tid >> 4;
    float4 a0 = {0, 0, 0, 0}, a1 = {0, 0, 0, 0};
    for (int k4 = 0; k4 < 128; k4 += 4) {
        float4 s0 = *(const float4*)&S2s[r0 * 132 + k4];
        float4 s1 = *(const float4*)&S2s[(r0 + 16) * 132 + k4];
        #pragma unroll
        for (int kk = 0; kk < 4; ++kk) {
            float v0 = (&s0.x)[kk];
            float v1 = (&s1.x)[kk];
            float4 w = *(const float4*)&Wc_s[(k4 + kk) * 64 + q];
            a0.x += v0 * w.x; a0.y += v0 * w.y; a0.z += v0 * w.z; a0.w += v0 * w.w;
            a1.x += v1 * w.x; a1.y += v1 * w.y; a1.z += v1 * w.z; a1.w += v1 * w.w;
        }
    }
    #pragma unroll
    for (int c = 0; c < 4; ++c) {
        Tt[(q + c) * 40 + r0]      = f2us((&a0.x)[c]);
        Tt[(q + c) * 40 + r0 + 16] = f2us((&a1.x)[c]);
    }
    __syncthreads();
    int cc = tid >> 4;              // 0..15
    int r  = (tid & 15) * 2;        // node pair
    int cg = (j0 >> 2) + cc;        // global concept
    #pragma unroll
    for (int rr = 0; rr < 2; ++rr) {
        ushort4 o;
        o.x = Tt[(cc * 4 + 0) * 40 + r + rr];
        o.y = Tt[(cc * 4 + 1) * 40 + r + rr];
        o.z = Tt[(cc * 4 + 2) * 40 + r + rr];
        o.w = Tt[(cc * 4 + 3) * 40 + r + rr];
        *(ushort4*)&mt4[((size_t)cg * N_NODES + n0 + r + rr) * 4] = o;
    }
}

// ---------------- nodez: 512 thr = 128 nodes x 4 concept-quarters (round-4 verified core) ----
// NEW: noise term folded in. Quarter q's concepts c in [8q,8q+8) use exactly Wrec rows
// [32q,32q+32) = the rows indexed by this quarter's noise slice, so z += sqrt(lambda)*noise
// before the rec accumulation reproduces (z + sqrt(l)*noise) @ Wrec with zero extra combine
// logic. brec added in the quarter-0 epilogue (wave-uniform s_loads). Replaces k_noisew
// entirely (saves its 51.2+12.8 MB pass and the 25.6 MB noiseW round-trip + one launch).
// Weight-load structure untouched (proven optimum; packed/8-split variants both regressed).
__global__ __launch_bounds__(512) void k_nodez(const unsigned short* __restrict__ mt4,
                                               const float* __restrict__ Wz1,
                                               const float* __restrict__ bz1,
                                               const float* __restrict__ Wz2,
                                               const float* __restrict__ bz2,
                                               const float* __restrict__ Wrec,
                                               const float* __restrict__ noise,
                                               const float* __restrict__ brec,
                                               float* __restrict__ out) {
    __shared__ float scr[3 * 128 * 34];            // 52.2 KB partial-combine scratch
    const float SQ = 0.03162277660168379f;         // sqrt(1e-3)
    int tid = threadIdx.x;
    int lt  = tid & 127;                           // node slot
    int qq  = tid >> 7;                            // concept quarter 0..3
    int c0  = __builtin_amdgcn_readfirstlane(qq * 8);
    int n = blockIdx.x * 128 + lt;
    bool ok = n < N_NODES;
    int m = ok ? n : (N_NODES - 1);

    const float4* W1 = (const float4*)Wz1;   // [c*32 + d*8 + g4]
    const float4* B1 = (const float4*)bz1;   // [c*8 + g4]
    const float4* W2 = (const float4*)Wz2;   // [c*32 + g]
    const float4* B2 = (const float4*)bz2;   // [c]
    const float4* WR = (const float4*)Wrec;  // [(c*4+d)*8 + o4]
    const float4* NZ = (const float4*)(noise + (size_t)m * 128);  // [c] per concept

    float4 o0 = {0,0,0,0}, o1 = {0,0,0,0}, o2 = {0,0,0,0}, o3 = {0,0,0,0};
    float4 o4v = {0,0,0,0}, o5 = {0,0,0,0}, o6 = {0,0,0,0}, o7 = {0,0,0,0};

    ushort4 mz = *(const ushort4*)&mt4[((size_t)c0 * N_NODES + m) * 4];

    for (int cc = 0; cc < 8; ++cc) {
        int c = c0 + cc;
        int cn = (cc < 7) ? (c + 1) : c;
        ushort4 nmz = *(const ushort4*)&mt4[((size_t)cn * N_NODES + m) * 4];
        float a0 = us2f(mz.x), a1 = us2f(mz.y), a2 = us2f(mz.z), a3 = us2f(mz.w);

        float4 zb = B2[c];
        float4 z = zb;
        #pragma unroll
        for (int g4 = 0; g4 < 8; ++g4) {
            float4 w0 = W1[c * 32 + g4];
            float4 w1 = W1[c * 32 + 8 + g4];
            float4 w2 = W1[c * 32 + 16 + g4];
            float4 w3 = W1[c * 32 + 24 + g4];
            float4 bb = B1[c * 8 + g4];
            float4 v;
            v.x = bb.x + a0 * w0.x + a1 * w1.x + a2 * w2.x + a3 * w3.x;
            v.y = bb.y + a0 * w0.y + a1 * w1.y + a2 * w2.y + a3 * w3.y;
            v.z = bb.z + a0 * w0.z + a1 * w1.z + a2 * w2.z + a3 * w3.z;
            v.w = bb.w + a0 * w0.w + a1 * w1.w + a2 * w2.w + a3 * w3.w;
            v.x = elu_fast(v.x); v.y = elu_fast(v.y); v.z = elu_fast(v.z); v.w = elu_fast(v.w);
            float4 u0 = W2[c * 32 + g4 * 4 + 0];
            float4 u1 = W2[c * 32 + g4 * 4 + 1];
            float4 u2 = W2[c * 32 + g4 * 4 + 2];
            float4 u3 = W2[c * 32 + g4 * 4 + 3];
            z.x += v.x * u0.x + v.y * u1.x + v.z * u2.x + v.w * u3.x;
            z.y += v.x * u0.y + v.y * u1.y + v.z * u2.y + v.w * u3.y;
            z.z += v.x * u0.z + v.y * u1.z + v.z * u2.z + v.w * u3.z;
            z.w += v.x * u0.w + v.y * u1.w + v.z * u2.w + v.w * u3.w;
        }
        // fold noise: z_total = z + sqrt(lambda) * noise[n][c*4 .. c*4+4]
        {
            float4 nz = NZ[c];
            z.x += SQ * nz.x; z.y += SQ * nz.y; z.z += SQ * nz.z; z.w += SQ * nz.w;
        }
        #pragma unroll
        for (int d = 0; d < 4; ++d) {
            float zv = (&z.x)[d];
            const float4* wr = &WR[(c * 4 + d) * 8];
            float4 r0 = wr[0], r1 = wr[1], r2 = wr[2], r3 = wr[3];
            float4 r4 = wr[4], r5 = wr[5], r6 = wr[6], r7 = wr[7];
            o0.x += zv * r0.x; o0.y += zv * r0.y; o0.z += zv * r0.z; o0.w += zv * r0.w;
            o1.x += zv * r1.x; o1.y += zv * r1.y; o1.z += zv * r1.z; o1.w += zv * r1.w;
            o2.x += zv * r2.x; o2.y += zv * r2.y; o2.z += zv * r2.z; o2.w += zv * r2.w;
            o3.x += zv * r3.x; o3.y += zv * r3.y; o3.z += zv * r3.z; o3.w += zv * r3.w;
            o4v.x += zv * r4.x; o4v.y += zv * r4.y; o4v.z += zv * r4.z; o4v.w += zv * r4.w;
            o5.x += zv * r5.x; o5.y += zv * r5.y; o5.z += zv * r5.z; o5.w += zv * r5.w;
            o6.x += zv * r6.x; o6.y += zv * r6.y; o6.z += zv * r6.z; o6.w += zv * r6.w;
            o7.x += zv * r7.x; o7.y += zv * r7.y; o7.z += zv * r7.z; o7.w += zv * r7.w;
        }
        mz = nmz;
    }

    // ---- combine quarters through LDS ----
    __syncthreads();
    if (qq != 0) {
        float* p = &scr[((qq - 1) * 128 + lt) * 34];
        *(float2*)&p[0]  = make_float2(o0.x, o0.y);  *(float2*)&p[2]  = make_float2(o0.z, o0.w);
        *(float2*)&p[4]  = make_float2(o1.x, o1.y);  *(float2*)&p[6]  = make_float2(o1.z, o1.w);
        *(float2*)&p[8]  = make_float2(o2.x, o2.y);  *(float2*)&p[10] = make_float2(o2.z, o2.w);
        *(float2*)&p[12] = make_float2(o3.x, o3.y);  *(float2*)&p[14] = make_float2(o3.z, o3.w);
        *(float2*)&p[16] = make_float2(o4v.x, o4v.y); *(float2*)&p[18] = make_float2(o4v.z, o4v.w);
        *(float2*)&p[20] = make_float2(o5.x, o5.y);  *(float2*)&p[22] = make_float2(o5.z, o5.w);
        *(float2*)&p[24] = make_float2(o6.x, o6.y);  *(float2*)&p[26] = make_float2(o6.z, o6.w);
        *(float2*)&p[28] = make_float2(o7.x, o7.y);  *(float2*)&p[30] = make_float2(o7.z, o7.w);
    }
    __syncthreads();
    if (qq == 0 && ok) {
        const float* pA = &scr[lt * 34];
        const float* pB = &scr[(128 + lt) * 34];
        const float* pC = &scr[(256 + lt) * 34];
        const float4* BR = (const float4*)brec;    // wave-uniform -> s_loads
        float4* po = (float4*)(out + (size_t)n * 32);
        float4 w, t;
        w = BR[0];
        t.x = o0.x + pA[0] + pB[0] + pC[0] + w.x;   t.y = o0.y + pA[1] + pB[1] + pC[1] + w.y;
        t.z = o0.z + pA[2] + pB[2] + pC[2] + w.z;   t.w = o0.w + pA[3] + pB[3] + pC[3] + w.w;
        po[0] = t;
        w = BR[1];
        t.x = o1.x + pA[4] + pB[4] + pC[4] + w.x;   t.y = o1.y + pA[5] + pB[5] + pC[5] + w.y;
        t.z = o1.z + pA[6] + pB[6] + pC[6] + w.z;   t.w = o1.w + pA[7] + pB[7] + pC[7] + w.w;
        po[1] = t;
        w = BR[2];
        t.x = o2.x + pA[8] + pB[8] + pC[8] + w.x;   t.y = o2.y + pA[9] + pB[9] + pC[9] + w.y;
        t.z = o2.z + pA[10] + pB[10] + pC[10] + w.z; t.w = o2.w + pA[11] + pB[11] + pC[11] + w.w;
        po[2] = t;
        w = BR[3];
        t.x = o3.x + pA[12] + pB[12] + pC[12] + w.x; t.y = o3.y + pA[13] + pB[13] + pC[13] + w.y;
        t.z = o3.z + pA[14] + pB[14] + pC[14] + w.z; t.w = o3.w + pA[15] + pB[15] + pC[15] + w.w;
        po[3] = t;
        w = BR[4];
        t.x = o4v.x + pA[16] + pB[16] + pC[16] + w.x; t.y = o4v.y + pA[17] + pB[17] + pC[17] + w.y;
        t.z = o4v.z + pA[18] + pB[18] + pC[18] + w.z; t.w = o4v.w + pA[19] + pB[19] + pC[19] + w.w;
        po[4] = t;
        w = BR[5];
        t.x = o5.x + pA[20] + pB[20] + pC[20] + w.x; t.y = o5.y + pA[21] + pB[21] + pC[21] + w.y;
        t.z = o5.z + pA[22] + pB[22] + pC[22] + w.z; t.w = o5.w + pA[23] + pB[23] + pC[23] + w.w;
        po[5] = t;
        w = BR[6];
        t.x = o6.x + pA[24] + pB[24] + pC[24] + w.x; t.y = o6.y + pA[25] + pB[25] + pC[25] + w.y;
        t.z = o6.z + pA[26] + pB[26] + pC[26] + w.z; t.w = o6.w + pA[27] + pB[27] + pC[27] + w.w;
        po[6] = t;
        w = BR[7];
        t.x = o7.x + pA[28] + pB[28] + pC[28] + w.x; t.y = o7.y + pA[29] + pB[29] + pC[29] + w.y;
        t.z = o7.z + pA[30] + pB[30] + pC[30] + w.z; t.w = o7.w + pA[31] + pB[31] + pC[31] + w.w;
        po[7] = t;
    }
}

// ---------------- label head: pred = MLP_c(A^T@label), one lane per node ---------------------
__global__ __launch_bounds__(256) void k_label(const float* __restrict__ label,
                                               const float* __restrict__ A,
                                               const float* __restrict__ Wl1,
                                               const float* __restrict__ bl1,
                                               const float* __restrict__ Wl2,
                                               const float* __restrict__ bl2,
                                               float* __restrict__ out) {
    __shared__ float As[1024], Wl1s[1024], bl1s[1024], Wl2s[1024], bl2s[32];
    int tid = threadIdx.x;
    for (int i = tid; i < 1024; i += 256) {
        As[i] = A[i];
        Wl1s[i] = Wl1[i];
        bl1s[i] = bl1[i];
        Wl2s[i] = Wl2[i];
    }
    if (tid < 32) bl2s[tid] = bl2[tid];
    __syncthreads();

    int n = blockIdx.x * 256 + tid;
    bool ok = n < N_NODES;
    int nn = ok ? n : (N_NODES - 1);

    float lab[32];
    #pragma unroll
    for (int q = 0; q < 8; ++q) {
        float4 lv = ((const float4*)(label + (size_t)nn * 32))[q];
        lab[q * 4 + 0] = lv.x; lab[q * 4 + 1] = lv.y;
        lab[q * 4 + 2] = lv.z; lab[q * 4 + 3] = lv.w;
    }
    float pred[32];
    for (int c = 0; c < 32; ++c) {
        float ml = 0.f;
        #pragma unroll
        for (int k = 0; k < 32; ++k) ml += As[k * 32 + c] * lab[k];
        float p = bl2s[c];
        #pragma unroll
        for (int g = 0; g < 32; ++g) {
            float h = elu_fast(ml * Wl1s[c * 32 + g] + bl1s[c * 32 + g]);
            p += h * Wl2s[c * 32 + g];
        }
        pred[c] = p;
    }
    if (ok) {
        #pragma unroll
        for (int q = 0; q < 8; ++q) {
            float4 v = {pred[q * 4 + 0], pred[q * 4 + 1], pred[q * 4 + 2], pred[q * 4 + 3]};
            ((float4*)(out + (size_t)N_NODES * 32 + (size_t)n * 32))[q] = v;
        }
    }
}

extern "C" void kernel_launch(void* const* d_in, const int* in_sizes, int n_in,
                              void* d_out, int out_size, void* d_ws, size_t ws_size,
                              hipStream_t stream) {
    const float* X      = (const float*)d_in[0];
    const float* label  = (const float*)d_in[1];
    const float* evalv  = (const float*)d_in[2];
    const float* noise  = (const float*)d_in[3];
    const float* W_base = (const float*)d_in[4];
    const float* W_mean = (const float*)d_in[5];
    // d_in[6] = W_logstd : dead code in the reference
    const float* A      = (const float*)d_in[7];
    const float* Wz1    = (const float*)d_in[8];
    const float* bz1    = (const float*)d_in[9];
    const float* Wz2    = (const float*)d_in[10];
    const float* bz2    = (const float*)d_in[11];
    const float* Wl1    = (const float*)d_in[12];
    const float* bl1    = (const float*)d_in[13];
    const float* Wl2    = (const float*)d_in[14];
    const float* bl2    = (const float*)d_in[15];
    const float* Wrec   = (const float*)d_in[16];
    const float* brec   = (const float*)d_in[17];
    const int* esrc = (const int*)d_in[18];
    const int* edst = (const int*)d_in[19];
    float* out = (float*)d_out;

    char* ws = (char*)d_ws;
    // Layout (~71.7 MB total; <= proven-safe 73.3 MB):
    float*          Wcomb        = (float*)(ws);                       // 64 KB
    unsigned int*   bucket_start = (unsigned int*)(ws + 71680);        // 392 u32
    unsigned int*   bucket_cursor= (unsigned int*)(ws + 73728);        // 391 u32
    unsigned int*   blk_hist     = (unsigned int*)(ws + 76800);        // 196*391 u32 = 306.5 KB
    unsigned int*   row_start    = (unsigned int*)(ws + 472064);       // N+1 u32
    uint2*          edge_sorted  = (uint2*)(ws + 1273984);             // 12.8 MB
    // slot A (25.6 MB): {coarse+coarse_dl scratch during bucket sort} -> hidden (bf16) -> mt4
    uint2*          coarse       = (uint2*)(ws + 14073984);            // 12.8 MB (dead before fuse1)
    unsigned char*  coarse_dl    = (unsigned char*)(ws + 26873984);    // 1.6 MB  (dead before fuse1)
    unsigned short* hidden       = (unsigned short*)(ws + 14073984);
    unsigned short* mt4          = (unsigned short*)(ws + 14073984);
    // slot B (25.6 MB): S2 (bf16); ends at 65273984
    unsigned short* S2           = (unsigned short*)(ws + 39673984);
    // Xh (bf16 X copy) past slot B end (round-5 aliasing lesson: never inside a live slot)
    unsigned short* Xh           = (unsigned short*)(ws + 65273984);   // 6.4 MB -> ends 71.7 MB

    k_prep<<<1, 1024, 0, stream>>>(A, W_mean, Wcomb);
    k_x16<<<800000 / 256, 256, 0, stream>>>(X, Xh);
    k_bhist<<<EHIST_G, 256, 0, stream>>>(edst, blk_hist);
    k_bscan<<<1, 512, 0, stream>>>(blk_hist, bucket_start, bucket_cursor);
    k_bucket1<<<EHIST_G, 256, 0, stream>>>(esrc, edst, evalv, blk_hist,
                                           bucket_cursor, coarse, coarse_dl);
    k_bucket2<<<NBUCK, 256, 0, stream>>>(bucket_start, coarse, coarse_dl,
                                         row_start, edge_sorted);
    k_fuse1<<<N_NODES / 8, 256, 0, stream>>>(row_start, edge_sorted, Xh, W_base, hidden);
    k_gather2<<<N_NODES / 8, 256, 0, stream>>>(row_start, edge_sorted, hidden, S2);
    k_gemm2<<<(N_NODES / 32) * 2, 256, 0, stream>>>(S2, Wcomb, mt4);
    k_nodez<<<(N_NODES + 127) / 128, 512, 0, stream>>>(mt4,
                                                       Wz1, bz1, Wz2, bz2,
                                                       Wrec, noise, brec, out);
    k_label<<<(N_NODES + 255) / 256, 256, 0, stream>>>(label, A, Wl1, bl1, Wl2, bl2, out);
}